// Round 11
// baseline (217.487 us; speedup 1.0000x reference)
//
#include <hip/hip_runtime.h>
#include <hip/hip_cooperative_groups.h>
#include <math.h>
#include <stdint.h>

namespace cg = cooperative_groups;

#define NEGV -1e9f
typedef float f32x4 __attribute__((ext_vector_type(4)));
typedef short bf16x8 __attribute__((ext_vector_type(8)));
typedef unsigned int u32x4 __attribute__((ext_vector_type(4)));

constexpr int B_ = 16, N_ = 1024, M_ = 128, D_ = 768;
constexpr int NCH = 12;   // 768/64 chunks
constexpr int NQP = 24;   // qlogp partials per (b,j)

// ws layout (bytes):
constexpr size_t OFF_QLOGP = 0;          // f32[16*128*24] = 196608
constexpr size_t OFF_PART  = 196608;     // 512 slots * 4096 B -> 2293760
constexpr size_t OFF_PIMG  = 2293760;    // 512 * 16384 -> 10682368 (fallback main1/main2)
constexpr size_t OFF_QIMG  = 10682368;   // QwH,QwL,QtH,QtL
constexpr size_t SZ_QIMG   = 3145728;
constexpr size_t WS_NEED   = OFF_QIMG + 4 * SZ_QIMG;  // ~23.3 MB
// R2-fallback aliases: qlog@0, rowmax@196608, wq2c@262144, bctx@327680

__device__ __forceinline__ unsigned short bf_rne(float x) {
    unsigned u = __float_as_uint(x);
    return (unsigned short)((u + 0x7fffu + ((u >> 16) & 1u)) >> 16);
}
__device__ __forceinline__ void splitf(float x, unsigned short& h, unsigned short& l) {
    unsigned short hb = bf_rne(x);
    float hf = __uint_as_float((unsigned)hb << 16);
    h = hb;
    l = bf_rne(x - hf);
}
__device__ __forceinline__ void gl_lds16(const void* g, void* l) {
    __builtin_amdgcn_global_load_lds(
        (const __attribute__((address_space(1))) void*)g,
        (__attribute__((address_space(3))) void*)l, 16, 0, 0);
}

// ---------------- k_prep2: col-split (b, chunk, half) -> 384 blocks ----------------
// QW (w3-folded): value[e]=Q[b, j=jh*64+jt*16+(lane&15), kb+(ks*4+(lane>>4))*8+e]*w3
// QT (raw):       value[e]=Q[b, j=(ks2*4+(lane>>4))*8+e, d=kb+jh3*32+dt*16+(lane&15)]
__global__ __launch_bounds__(256) void k_prep2(const float* __restrict__ Q,
                                               const float* __restrict__ w2,
                                               const float* __restrict__ w3,
                                               char* __restrict__ qwh, char* __restrict__ qwl,
                                               char* __restrict__ qth, char* __restrict__ qtl,
                                               float* __restrict__ qlogp) {
    const int bi = blockIdx.x;
    const int b = bi / (NCH * 2), rem = bi % (NCH * 2);
    const int c = rem >> 1, half = rem & 1;
    const int t = threadIdx.x;
    __shared__ unsigned sT[128][33];
    __shared__ float sW2h[32], sW3h[32];
    if (t < 32) sW2h[t] = w2[c * 64 + half * 32 + t];
    else if (t < 64) sW3h[t - 32] = w3[c * 64 + half * 32 + (t - 32)];
    __syncthreads();
    const int j = t >> 1, h16 = t & 1;
    const float* src = Q + ((size_t)(b * M_ + j)) * D_ + c * 64 + half * 32 + h16 * 16;
    unsigned short hs[16], ls[16];
    float qsum = 0.f;
#pragma unroll
    for (int u = 0; u < 4; ++u) {
        float4 v = *(const float4*)(src + u * 4);
        float f[4] = {v.x, v.y, v.z, v.w};
#pragma unroll
        for (int e = 0; e < 4; ++e) {
            int idx = u * 4 + e;          // 0..15 within thread
            int lc  = h16 * 16 + idx;     // 0..31 within half
            qsum += f[e] * sW2h[lc];
            unsigned short rh, rl; splitf(f[e], rh, rl);
            sT[j][lc] = ((unsigned)rh << 16) | (unsigned)rl;
            unsigned short h, l; splitf(f[e] * sW3h[lc], h, l);
            hs[idx] = h; ls[idx] = l;
        }
    }
    qsum += __shfl_xor(qsum, 1);
    if (h16 == 0) qlogp[(size_t)(b * M_ + j) * NQP + c * 2 + half] = qsum;
    size_t cb = ((size_t)(b * NCH + c)) * 16384;
    {   // QW fragment writes: groups g = half*4 + h16*2 + u2
        int jh = j >> 6, jt = (j >> 4) & 3, c15j = j & 15;
#pragma unroll
        for (int u2 = 0; u2 < 2; ++u2) {
            int g = half * 4 + h16 * 2 + u2, ks = g >> 2, q4g = g & 3;
            int lane = q4g * 16 + c15j;
            bf16x8 hv, lv;
#pragma unroll
            for (int e = 0; e < 8; ++e) { hv[e] = (short)hs[u2 * 8 + e]; lv[e] = (short)ls[u2 * 8 + e]; }
            size_t off = cb + (size_t)((((jh * 2 + ks) * 4 + jt) * 64 + lane) * 16);
            *(bf16x8*)(qwh + off) = hv;
            *(bf16x8*)(qwl + off) = lv;
        }
    }
    __syncthreads();
    // QT fragment writes: dd = half*32 + dd_loc
#pragma unroll
    for (int u = 0; u < 2; ++u) {
        int id = t * 2 + u;
        int dd_loc = id >> 4, gj = id & 15;
        int dt = dd_loc >> 4, c15q = dd_loc & 15;
        int ks2 = gj >> 2, q4g = gj & 3;
        int lane = q4g * 16 + c15q;
        bf16x8 hv, lv;
#pragma unroll
        for (int e = 0; e < 8; ++e) {
            unsigned p = sT[gj * 8 + e][dd_loc];
            hv[e] = (short)(p >> 16); lv[e] = (short)(p & 0xffffu);
        }
        size_t off = cb + (size_t)((((half * 4 + ks2) * 2 + dt) * 64 + lane) * 16);
        *(bf16x8*)(qth + off) = hv;
        *(bf16x8*)(qtl + off) = lv;
    }
}

// ---------------- k_mainc: cooperative fused main (phases 1+2 | sync | combine+3) ----------------
__global__ __launch_bounds__(256, 3) void k_mainc(const float* __restrict__ C,
                                                  const int* __restrict__ c_mask,
                                                  const int* __restrict__ q_mask,
                                                  const float* __restrict__ w1,
                                                  const float* __restrict__ qlogp,
                                                  const char* __restrict__ qwh,
                                                  const char* __restrict__ qwl,
                                                  const char* __restrict__ qth,
                                                  const char* __restrict__ qtl,
                                                  float* __restrict__ part,
                                                  float* __restrict__ out) {
    cg::grid_group grid = cg::this_grid();
    const int bid = (blockIdx.x & 7) * 64 + (blockIdx.x >> 3);  // XCD-chunked, bijective
    const int b  = bid >> 5;
    const int r0 = (bid & 31) * 32;
    const int t  = threadIdx.x;
    const int wv = t >> 6, lane = t & 63;
    const int rg = wv >> 1, jh = wv & 1;
    const int q4 = lane >> 4, c15 = t & 15;

    const float* Cb = C + ((size_t)(b * N_ + r0)) * D_;

    __shared__ __align__(16) char uni[49152];
    __shared__ float sQlog[M_];
    __shared__ int   sQmask[M_];
    __shared__ float sClog[32], sMraw[32], sMl[32], sWr[32];
    __shared__ float sRedR[64], sRedM[64], sRedS[64];
    __shared__ float sLm[32], sDen[32], sSc[32];

    char*  sQH   = uni;                    // phase1 B staging (16 KB)
    char*  sQL   = uni + 16384;
    char*  sPH   = uni + 32768;            // P image (8 KB) — phase-2 tail
    char*  sPL   = uni + 40960;
    float* sW1   = (float*)(uni + 32768);  // aliases sPH; dead before P store
    float* sBctx = (float*)(uni + 32768);  // aliases sPH; used AFTER pah in regs
    char*  sQtH  = uni;                    // phase3 staging (aliases sQH)
    char*  sQtL  = uni + 16384;

    for (int k = t; k < D_; k += 256) sW1[k] = w1[k];
    if (t < M_) {
        const float* qp = qlogp + (size_t)(b * M_ + t) * NQP;
        float s = 0.f;
#pragma unroll
        for (int u = 0; u < 6; ++u) {
            float4 v = ((const float4*)qp)[u];
            s += (v.x + v.y) + (v.z + v.w);
        }
        sQlog[t] = s;
        sQmask[t] = q_mask[b * M_ + t];
    }
    __syncthreads();

    f32x4 acc[4] = {};
    float clogp = 0.f;
    const int arow = rg * 16 + c15;
    const float* CbA = Cb + (size_t)arow * D_;
    const size_t qcb = (size_t)(b * NCH) * 16384;

    // ---- Phase 1: S = C @ (w3*Q)^T ----
    for (int kidx = 0; kidx < NCH; ++kidx) {
        __syncthreads();
        {
            size_t gb = qcb + (size_t)kidx * 16384;
#pragma unroll
            for (int it = 0; it < 4; ++it) {
                int qo = it * 4096 + wv * 1024;
                gl_lds16(qwh + gb + qo + lane * 16, sQH + qo);
                gl_lds16(qwl + gb + qo + lane * 16, sQL + qo);
            }
        }
        bf16x8 ah[2], al[2];
        const int kb = kidx * 64;
#pragma unroll
        for (int ks = 0; ks < 2; ++ks) {
            const int k0 = kb + (ks * 4 + q4) * 8;
            float4 ca  = *(const float4*)(CbA + k0);
            float4 cb2 = *(const float4*)(CbA + k0 + 4);
            float cc[8] = {ca.x, ca.y, ca.z, ca.w, cb2.x, cb2.y, cb2.z, cb2.w};
#pragma unroll
            for (int e = 0; e < 8; ++e) {
                clogp += cc[e] * sW1[k0 + e];
                unsigned short h, l; splitf(cc[e], h, l);
                ah[ks][e] = (short)h; al[ks][e] = (short)l;
            }
        }
        __syncthreads();
#pragma unroll
        for (int ks = 0; ks < 2; ++ks) {
#pragma unroll
            for (int jt = 0; jt < 4; ++jt) {
                int fo = (((jh * 2 + ks) * 4 + jt) * 64 + lane) * 16;
                bf16x8 bh = *(const bf16x8*)(sQH + fo);
                bf16x8 bl = *(const bf16x8*)(sQL + fo);
                acc[jt] = __builtin_amdgcn_mfma_f32_16x16x32_bf16(ah[ks], bh, acc[jt], 0, 0, 0);
                acc[jt] = __builtin_amdgcn_mfma_f32_16x16x32_bf16(ah[ks], bl, acc[jt], 0, 0, 0);
                acc[jt] = __builtin_amdgcn_mfma_f32_16x16x32_bf16(al[ks], bh, acc[jt], 0, 0, 0);
            }
        }
    }
    clogp += __shfl_xor(clogp, 16);
    clogp += __shfl_xor(clogp, 32);
    if (jh == 0 && q4 == 0) sClog[arow] = clogp;
    __syncthreads();

    // ---- Phase 2: logits + masked softmax ----
    float qlg[4]; int qmv[4];
#pragma unroll
    for (int jt = 0; jt < 4; ++jt) {
        int j = jh * 64 + jt * 16 + c15;
        qlg[jt] = sQlog[j]; qmv[jt] = sQmask[j];
    }
    int cmv[4]; float clgr[4];
#pragma unroll
    for (int rr = 0; rr < 4; ++rr) {
        int row = rg * 16 + q4 * 4 + rr;
        cmv[rr]  = c_mask[b * N_ + r0 + row];
        clgr[rr] = sClog[row];
    }
    float mv[4][4], rmx[4], mmx[4];
#pragma unroll
    for (int rr = 0; rr < 4; ++rr) { rmx[rr] = -INFINITY; mmx[rr] = -INFINITY; }
#pragma unroll
    for (int jt = 0; jt < 4; ++jt)
#pragma unroll
        for (int rr = 0; rr < 4; ++rr) {
            float val = acc[jt][rr] + clgr[rr] + qlg[jt];
            float m   = (cmv[rr] | qmv[jt]) ? NEGV : val;
            mv[jt][rr] = m;
            rmx[rr] = fmaxf(rmx[rr], val);
            mmx[rr] = fmaxf(mmx[rr], m);
        }
#pragma unroll
    for (int rr = 0; rr < 4; ++rr)
#pragma unroll
        for (int off = 8; off; off >>= 1) {
            rmx[rr] = fmaxf(rmx[rr], __shfl_xor(rmx[rr], off));
            mmx[rr] = fmaxf(mmx[rr], __shfl_xor(mmx[rr], off));
        }
    if (c15 == 0) {
#pragma unroll
        for (int rr = 0; rr < 4; ++rr) {
            int row = rg * 16 + q4 * 4 + rr;
            sRedR[row * 2 + jh] = rmx[rr];
            sRedM[row * 2 + jh] = mmx[rr];
        }
    }
    __syncthreads();
    float Mm[4], sum[4];
#pragma unroll
    for (int rr = 0; rr < 4; ++rr) {
        int row = rg * 16 + q4 * 4 + rr;
        float Mraw = fmaxf(sRedR[row * 2], sRedR[row * 2 + 1]);
        Mm[rr] = fmaxf(sRedM[row * 2], sRedM[row * 2 + 1]);
        if (jh == 0 && c15 == 0) sMraw[row] = Mraw;
        sum[rr] = 0.f;
    }
    float p[4][4];
#pragma unroll
    for (int jt = 0; jt < 4; ++jt)
#pragma unroll
        for (int rr = 0; rr < 4; ++rr) {
            float e = __expf(mv[jt][rr] - Mm[rr]);
            p[jt][rr] = e; sum[rr] += e;
        }
#pragma unroll
    for (int rr = 0; rr < 4; ++rr) {
#pragma unroll
        for (int off = 8; off; off >>= 1) sum[rr] += __shfl_xor(sum[rr], off);
        if (c15 == 0) sRedS[(rg * 16 + q4 * 4 + rr) * 2 + jh] = sum[rr];
    }
    __syncthreads();   // sW1 (alias sPH) dead past here
#pragma unroll
    for (int rr = 0; rr < 4; ++rr) {
        int row = rg * 16 + q4 * 4 + rr;
        float inv = 1.f / (sRedS[row * 2] + sRedS[row * 2 + 1]);
#pragma unroll
        for (int jt = 0; jt < 4; ++jt) {
            float P = p[jt][rr] * inv;
            unsigned short h, l; splitf(P, h, l);
            int j = jh * 64 + jt * 16 + c15;
            int addr = row * 256 + (((j >> 3) ^ (row & 7)) * 16) + (j & 7) * 2;
            *(short*)(sPH + addr) = (short)h;
            *(short*)(sPL + addr) = (short)l;
        }
    }
    __syncthreads();

    // ---- hoist P to registers (persists across grid.sync) ----
    bf16x8 pah[4], pal[4];
    const int prow = rg * 16 + c15;
#pragma unroll
    for (int ks2 = 0; ks2 < 4; ++ks2) {
        int gja = ks2 * 4 + q4;
        int pgp = (gja ^ (prow & 7)) * 16;
        pah[ks2] = *(const bf16x8*)(sPH + prow * 256 + pgp);
        pal[ks2] = *(const bf16x8*)(sPL + prow * 256 + pgp);
    }

    // ---- Bctx partials (online softmax over this block's 32 rows) ----
    if (t < 32) sMl[t] = (c_mask[b * N_ + r0 + t] != 0) ? NEGV : sMraw[t];
    __syncthreads();
    float lm = -INFINITY;
#pragma unroll
    for (int r = 0; r < 32; ++r) lm = fmaxf(lm, sMl[r]);
    if (t < 32) sWr[t] = __expf(sMl[t] - lm);
    __syncthreads();
    float den = 0.f;
#pragma unroll
    for (int r = 0; r < 32; ++r) den += sWr[r];
    {
        float a0 = 0.f, a1 = 0.f, a2 = 0.f;
        for (int r = 0; r < 32; ++r) {
            float w = sWr[r];
            if (w != 0.f) {
                const float* cr = Cb + (size_t)r * D_;
                a0 += w * cr[t]; a1 += w * cr[t + 256]; a2 += w * cr[t + 512];
            }
        }
        float* slot = part + (size_t)bid * 1024;
        slot[2 + t] = a0; slot[2 + t + 256] = a1; slot[2 + t + 512] = a2;
        if (t == 0) { slot[0] = lm; slot[1] = den; }
    }
    __threadfence();
    grid.sync();

    // ---- inline combine: exact Bctx -> sBctx (aliases sPH; P already in regs) ----
    if (t < 32) {
        const float* s = part + (size_t)(b * 32 + t) * 1024;
        sLm[t] = s[0]; sDen[t] = s[1];
    }
    __syncthreads();
    {
        float gm = -INFINITY;
#pragma unroll
        for (int r = 0; r < 32; ++r) gm = fmaxf(gm, sLm[r]);
        if (t < 32) sSc[t] = __expf(sLm[t] - gm);
        __syncthreads();
        float Ds = 0.f;
#pragma unroll
        for (int r = 0; r < 32; ++r) Ds += sDen[r] * sSc[r];
        float inv = 1.f / Ds;
#pragma unroll
        for (int u = 0; u < 3; ++u) {
            int col = t + u * 256;
            float a = 0.f;
            for (int rt = 0; rt < 32; ++rt)
                a += sSc[rt] * part[(size_t)(b * 32 + rt) * 1024 + 2 + col];
            sBctx[col] = a * inv;
        }
    }
    __syncthreads();

    // ---- Phase 3: A = P @ Q + 4-quarter epilogue ----
    const size_t qcb3 = (size_t)(b * NCH) * 16384;
    for (int dc = 0; dc < NCH; ++dc) {
        __syncthreads();
        {
            size_t gb = qcb3 + (size_t)dc * 16384;
#pragma unroll
            for (int it = 0; it < 4; ++it) {
                int qo = it * 4096 + wv * 1024;
                gl_lds16(qth + gb + qo + lane * 16, sQtH + qo);
                gl_lds16(qtl + gb + qo + lane * 16, sQtL + qo);
            }
        }
        float cpre[2][4], gpre[2];
#pragma unroll
        for (int dt = 0; dt < 2; ++dt) {
            int dcol = dc * 64 + jh * 32 + dt * 16 + c15;
            gpre[dt] = sBctx[dcol];
#pragma unroll
            for (int rr = 0; rr < 4; ++rr) {
                int row = rg * 16 + q4 * 4 + rr;
                cpre[dt][rr] = Cb[(size_t)row * D_ + dcol];
            }
        }
        __syncthreads();
        f32x4 acc2[2] = {};
#pragma unroll
        for (int ks2 = 0; ks2 < 4; ++ks2) {
#pragma unroll
            for (int dt = 0; dt < 2; ++dt) {
                int fo = (((jh * 4 + ks2) * 2 + dt) * 64 + lane) * 16;
                bf16x8 bh = *(const bf16x8*)(sQtH + fo);
                bf16x8 bl = *(const bf16x8*)(sQtL + fo);
                acc2[dt] = __builtin_amdgcn_mfma_f32_16x16x32_bf16(pah[ks2], bh, acc2[dt], 0, 0, 0);
                acc2[dt] = __builtin_amdgcn_mfma_f32_16x16x32_bf16(pah[ks2], bl, acc2[dt], 0, 0, 0);
                acc2[dt] = __builtin_amdgcn_mfma_f32_16x16x32_bf16(pal[ks2], bh, acc2[dt], 0, 0, 0);
            }
        }
#pragma unroll
        for (int dt = 0; dt < 2; ++dt) {
            int dcol = dc * 64 + jh * 32 + dt * 16 + c15;
            float g = gpre[dt];
#pragma unroll
            for (int rr = 0; rr < 4; ++rr) {
                int row = rg * 16 + q4 * 4 + rr;
                float a = acc2[dt][rr];
                float c = cpre[dt][rr];
                size_t ob = (size_t)(b * N_ + r0 + row) * 3072;
                out[ob + dcol] = c;
                out[ob + 768 + dcol] = a;
                out[ob + 1536 + dcol] = c * a;
                out[ob + 2304 + dcol] = c * g;
            }
        }
    }
}

// ---------------- k_main1/k_main2 fallback (R10-proven; qlogp-24) ----------------
__global__ __launch_bounds__(256, 3) void k_main1(const float* __restrict__ C,
                                                  const int* __restrict__ c_mask,
                                                  const int* __restrict__ q_mask,
                                                  const float* __restrict__ w1,
                                                  const float* __restrict__ qlogp,
                                                  const char* __restrict__ qwh,
                                                  const char* __restrict__ qwl,
                                                  float* __restrict__ part,
                                                  char* __restrict__ pimg) {
    const int bid = (blockIdx.x & 7) * 64 + (blockIdx.x >> 3);
    const int b  = bid >> 5;
    const int r0 = (bid & 31) * 32;
    const int t  = threadIdx.x;
    const int wv = t >> 6, lane = t & 63;
    const int rg = wv >> 1, jh = wv & 1;
    const int q4 = lane >> 4, c15 = t & 15;

    const float* Cb = C + ((size_t)(b * N_ + r0)) * D_;

    __shared__ __align__(16) char uni[49152];
    __shared__ float sQlog[M_];
    __shared__ int   sQmask[M_];
    __shared__ float sClog[32], sMraw[32], sMl[32], sWr[32];
    __shared__ float sRedR[64], sRedM[64], sRedS[64];

    char* sQH = uni;
    char* sQL = uni + 16384;
    char* sPH = uni + 32768;
    char* sPL = uni + 40960;
    float* sW1 = (float*)(uni + 32768);

    for (int k = t; k < D_; k += 256) sW1[k] = w1[k];
    if (t < M_) {
        const float* qp = qlogp + (size_t)(b * M_ + t) * NQP;
        float s = 0.f;
#pragma unroll
        for (int u = 0; u < 6; ++u) {
            float4 v = ((const float4*)qp)[u];
            s += (v.x + v.y) + (v.z + v.w);
        }
        sQlog[t] = s;
        sQmask[t] = q_mask[b * M_ + t];
    }
    __syncthreads();

    f32x4 acc[4] = {};
    float clogp = 0.f;
    const int arow = rg * 16 + c15;
    const float* CbA = Cb + (size_t)arow * D_;
    const size_t qcb = (size_t)(b * NCH) * 16384;

    for (int kidx = 0; kidx < NCH; ++kidx) {
        __syncthreads();
        {
            size_t gb = qcb + (size_t)kidx * 16384;
#pragma unroll
            for (int it = 0; it < 4; ++it) {
                int qo = it * 4096 + wv * 1024;
                gl_lds16(qwh + gb + qo + lane * 16, sQH + qo);
                gl_lds16(qwl + gb + qo + lane * 16, sQL + qo);
            }
        }
        bf16x8 ah[2], al[2];
        const int kb = kidx * 64;
#pragma unroll
        for (int ks = 0; ks < 2; ++ks) {
            const int k0 = kb + (ks * 4 + q4) * 8;
            float4 ca  = *(const float4*)(CbA + k0);
            float4 cb2 = *(const float4*)(CbA + k0 + 4);
            float cc[8] = {ca.x, ca.y, ca.z, ca.w, cb2.x, cb2.y, cb2.z, cb2.w};
#pragma unroll
            for (int e = 0; e < 8; ++e) {
                clogp += cc[e] * sW1[k0 + e];
                unsigned short h, l; splitf(cc[e], h, l);
                ah[ks][e] = (short)h; al[ks][e] = (short)l;
            }
        }
        __syncthreads();
#pragma unroll
        for (int ks = 0; ks < 2; ++ks) {
#pragma unroll
            for (int jt = 0; jt < 4; ++jt) {
                int fo = (((jh * 2 + ks) * 4 + jt) * 64 + lane) * 16;
                bf16x8 bh = *(const bf16x8*)(sQH + fo);
                bf16x8 bl = *(const bf16x8*)(sQL + fo);
                acc[jt] = __builtin_amdgcn_mfma_f32_16x16x32_bf16(ah[ks], bh, acc[jt], 0, 0, 0);
                acc[jt] = __builtin_amdgcn_mfma_f32_16x16x32_bf16(ah[ks], bl, acc[jt], 0, 0, 0);
                acc[jt] = __builtin_amdgcn_mfma_f32_16x16x32_bf16(al[ks], bh, acc[jt], 0, 0, 0);
            }
        }
    }
    clogp += __shfl_xor(clogp, 16);
    clogp += __shfl_xor(clogp, 32);
    if (jh == 0 && q4 == 0) sClog[arow] = clogp;
    __syncthreads();

    float qlg[4]; int qmv[4];
#pragma unroll
    for (int jt = 0; jt < 4; ++jt) {
        int j = jh * 64 + jt * 16 + c15;
        qlg[jt] = sQlog[j]; qmv[jt] = sQmask[j];
    }
    int cmv[4]; float clgr[4];
#pragma unroll
    for (int rr = 0; rr < 4; ++rr) {
        int row = rg * 16 + q4 * 4 + rr;
        cmv[rr]  = c_mask[b * N_ + r0 + row];
        clgr[rr] = sClog[row];
    }
    float mv[4][4], rmx[4], mmx[4];
#pragma unroll
    for (int rr = 0; rr < 4; ++rr) { rmx[rr] = -INFINITY; mmx[rr] = -INFINITY; }
#pragma unroll
    for (int jt = 0; jt < 4; ++jt)
#pragma unroll
        for (int rr = 0; rr < 4; ++rr) {
            float val = acc[jt][rr] + clgr[rr] + qlg[jt];
            float m   = (cmv[rr] | qmv[jt]) ? NEGV : val;
            mv[jt][rr] = m;
            rmx[rr] = fmaxf(rmx[rr], val);
            mmx[rr] = fmaxf(mmx[rr], m);
        }
#pragma unroll
    for (int rr = 0; rr < 4; ++rr)
#pragma unroll
        for (int off = 8; off; off >>= 1) {
            rmx[rr] = fmaxf(rmx[rr], __shfl_xor(rmx[rr], off));
            mmx[rr] = fmaxf(mmx[rr], __shfl_xor(mmx[rr], off));
        }
    if (c15 == 0) {
#pragma unroll
        for (int rr = 0; rr < 4; ++rr) {
            int row = rg * 16 + q4 * 4 + rr;
            sRedR[row * 2 + jh] = rmx[rr];
            sRedM[row * 2 + jh] = mmx[rr];
        }
    }
    __syncthreads();
    float Mm[4], sum[4];
#pragma unroll
    for (int rr = 0; rr < 4; ++rr) {
        int row = rg * 16 + q4 * 4 + rr;
        float Mraw = fmaxf(sRedR[row * 2], sRedR[row * 2 + 1]);
        Mm[rr] = fmaxf(sRedM[row * 2], sRedM[row * 2 + 1]);
        if (jh == 0 && c15 == 0) sMraw[row] = Mraw;
        sum[rr] = 0.f;
    }
    float p[4][4];
#pragma unroll
    for (int jt = 0; jt < 4; ++jt)
#pragma unroll
        for (int rr = 0; rr < 4; ++rr) {
            float e = __expf(mv[jt][rr] - Mm[rr]);
            p[jt][rr] = e; sum[rr] += e;
        }
#pragma unroll
    for (int rr = 0; rr < 4; ++rr) {
#pragma unroll
        for (int off = 8; off; off >>= 1) sum[rr] += __shfl_xor(sum[rr], off);
        if (c15 == 0) sRedS[(rg * 16 + q4 * 4 + rr) * 2 + jh] = sum[rr];
    }
    __syncthreads();
#pragma unroll
    for (int rr = 0; rr < 4; ++rr) {
        int row = rg * 16 + q4 * 4 + rr;
        float inv = 1.f / (sRedS[row * 2] + sRedS[row * 2 + 1]);
#pragma unroll
        for (int jt = 0; jt < 4; ++jt) {
            float P = p[jt][rr] * inv;
            unsigned short h, l; splitf(P, h, l);
            int j = jh * 64 + jt * 16 + c15;
            int addr = row * 256 + (((j >> 3) ^ (row & 7)) * 16) + (j & 7) * 2;
            *(short*)(sPH + addr) = (short)h;
            *(short*)(sPL + addr) = (short)l;
        }
    }
    __syncthreads();

    if (t < 32) sMl[t] = (c_mask[b * N_ + r0 + t] != 0) ? NEGV : sMraw[t];
    __syncthreads();
    float lm = -INFINITY;
#pragma unroll
    for (int r = 0; r < 32; ++r) lm = fmaxf(lm, sMl[r]);
    if (t < 32) sWr[t] = __expf(sMl[t] - lm);
    __syncthreads();
    float den = 0.f;
#pragma unroll
    for (int r = 0; r < 32; ++r) den += sWr[r];
    {
        float a0 = 0.f, a1 = 0.f, a2 = 0.f;
        for (int r = 0; r < 32; ++r) {
            float w = sWr[r];
            if (w != 0.f) {
                const float* cr = Cb + (size_t)r * D_;
                a0 += w * cr[t]; a1 += w * cr[t + 256]; a2 += w * cr[t + 512];
            }
        }
        float* slot = part + (size_t)bid * 1024;
        slot[2 + t] = a0; slot[2 + t + 256] = a1; slot[2 + t + 512] = a2;
        if (t == 0) { slot[0] = lm; slot[1] = den; }
    }
#pragma unroll
    for (int i = 0; i < 2; ++i) {
        *(u32x4*)(pimg + (size_t)bid * 16384 + t * 32 + i * 16) =
            *(const u32x4*)(sPH + t * 32 + i * 16);
        *(u32x4*)(pimg + (size_t)bid * 16384 + 8192 + t * 32 + i * 16) =
            *(const u32x4*)(sPL + t * 32 + i * 16);
    }
}

__global__ __launch_bounds__(256, 3) void k_main2(const float* __restrict__ C,
                                                  const float* __restrict__ part,
                                                  const char* __restrict__ qth,
                                                  const char* __restrict__ qtl,
                                                  const char* __restrict__ pimg,
                                                  float* __restrict__ out) {
    const int bid = (blockIdx.x & 7) * 64 + (blockIdx.x >> 3);
    const int b  = bid >> 5;
    const int r0 = (bid & 31) * 32;
    const int t  = threadIdx.x;
    const int wv = t >> 6, lane = t & 63;
    const int rg = wv >> 1, jh = wv & 1;
    const int q4 = lane >> 4, c15 = t & 15;

    const float* Cb = C + ((size_t)(b * N_ + r0)) * D_;

    __shared__ __align__(16) char uni[49152];
    __shared__ float sBctx[D_];
    __shared__ float sLm[32], sDen[32], sSc[32];
    char* sQtH = uni;
    char* sQtL = uni + 16384;
    char* sPH  = uni + 32768;
    char* sPL  = uni + 40960;

    {
        const char* ps = pimg + (size_t)bid * 16384;
#pragma unroll
        for (int it = 0; it < 2; ++it) {
            int off = it * 4096 + wv * 1024;
            gl_lds16(ps + off + lane * 16, sPH + off);
            gl_lds16(ps + 8192 + off + lane * 16, sPL + off);
        }
    }
    if (t < 32) {
        const float* s = part + (size_t)(b * 32 + t) * 1024;
        sLm[t] = s[0]; sDen[t] = s[1];
    }
    __syncthreads();
    {
        float gm = -INFINITY;
#pragma unroll
        for (int r = 0; r < 32; ++r) gm = fmaxf(gm, sLm[r]);
        if (t < 32) sSc[t] = __expf(sLm[t] - gm);
        __syncthreads();
        float Ds = 0.f;
#pragma unroll
        for (int r = 0; r < 32; ++r) Ds += sDen[r] * sSc[r];
        float inv = 1.f / Ds;
#pragma unroll
        for (int u = 0; u < 3; ++u) {
            int col = t + u * 256;
            float a = 0.f;
            for (int rt = 0; rt < 32; ++rt)
                a += sSc[rt] * part[(size_t)(b * 32 + rt) * 1024 + 2 + col];
            sBctx[col] = a * inv;
        }
    }
    __syncthreads();

    bf16x8 pah[4], pal[4];
    const int prow = rg * 16 + c15;
#pragma unroll
    for (int ks2 = 0; ks2 < 4; ++ks2) {
        int gja = ks2 * 4 + q4;
        int pgp = (gja ^ (prow & 7)) * 16;
        pah[ks2] = *(const bf16x8*)(sPH + prow * 256 + pgp);
        pal[ks2] = *(const bf16x8*)(sPL + prow * 256 + pgp);
    }

    const size_t qcb = (size_t)(b * NCH) * 16384;
    for (int dc = 0; dc < NCH; ++dc) {
        __syncthreads();
        {
            size_t gb = qcb + (size_t)dc * 16384;
#pragma unroll
            for (int it = 0; it < 4; ++it) {
                int qo = it * 4096 + wv * 1024;
                gl_lds16(qth + gb + qo + lane * 16, sQtH + qo);
                gl_lds16(qtl + gb + qo + lane * 16, sQtL + qo);
            }
        }
        float cpre[2][4], gpre[2];
#pragma unroll
        for (int dt = 0; dt < 2; ++dt) {
            int dcol = dc * 64 + jh * 32 + dt * 16 + c15;
            gpre[dt] = sBctx[dcol];
#pragma unroll
            for (int rr = 0; rr < 4; ++rr) {
                int row = rg * 16 + q4 * 4 + rr;
                cpre[dt][rr] = Cb[(size_t)row * D_ + dcol];
            }
        }
        __syncthreads();
        f32x4 acc2[2] = {};
#pragma unroll
        for (int ks2 = 0; ks2 < 4; ++ks2) {
#pragma unroll
            for (int dt = 0; dt < 2; ++dt) {
                int fo = (((jh * 4 + ks2) * 2 + dt) * 64 + lane) * 16;
                bf16x8 bh = *(const bf16x8*)(sQtH + fo);
                bf16x8 bl = *(const bf16x8*)(sQtL + fo);
                acc2[dt] = __builtin_amdgcn_mfma_f32_16x16x32_bf16(pah[ks2], bh, acc2[dt], 0, 0, 0);
                acc2[dt] = __builtin_amdgcn_mfma_f32_16x16x32_bf16(pah[ks2], bl, acc2[dt], 0, 0, 0);
                acc2[dt] = __builtin_amdgcn_mfma_f32_16x16x32_bf16(pal[ks2], bh, acc2[dt], 0, 0, 0);
            }
        }
#pragma unroll
        for (int dt = 0; dt < 2; ++dt) {
            int dcol = dc * 64 + jh * 32 + dt * 16 + c15;
            float g = gpre[dt];
#pragma unroll
            for (int rr = 0; rr < 4; ++rr) {
                int row = rg * 16 + q4 * 4 + rr;
                float a = acc2[dt][rr];
                float c = cpre[dt][rr];
                size_t ob = (size_t)(b * N_ + r0 + row) * 3072;
                out[ob + dcol] = c;
                out[ob + 768 + dcol] = a;
                out[ob + 1536 + dcol] = c * a;
                out[ob + 2304 + dcol] = c * g;
            }
        }
    }
}

// ---------------- R2-proven full-fallback chain ----------------
__global__ __launch_bounds__(256) void k_qlogit(const float* __restrict__ Q,
                                                const float* __restrict__ w2,
                                                float* __restrict__ qlog) {
    int idx  = blockIdx.x * 4 + (threadIdx.x >> 6);
    int lane = threadIdx.x & 63;
    const float* q = Q + (size_t)idx * D_;
    float s = 0.f;
    for (int k = lane; k < D_; k += 64) s += q[k] * w2[k];
#pragma unroll
    for (int off = 32; off; off >>= 1) s += __shfl_xor(s, off);
    if (lane == 0) qlog[idx] = s;
}

__global__ __launch_bounds__(256, 2) void k_main_fb(const float* __restrict__ C,
                                                    const float* __restrict__ Q,
                                                    const int* __restrict__ c_mask,
                                                    const int* __restrict__ q_mask,
                                                    const float* __restrict__ w1,
                                                    const float* __restrict__ w3,
                                                    const float* __restrict__ qlog,
                                                    float* __restrict__ rowmax,
                                                    float* __restrict__ out) {
    const int bid = (blockIdx.x & 7) * 64 + (blockIdx.x >> 3);
    const int b  = bid >> 5;
    const int r0 = (bid & 31) * 32;
    const int t  = threadIdx.x;
    const int wv = t >> 6;
    const int rg = wv >> 1, jh = wv & 1;
    const int q4 = (t & 63) >> 4, c15 = t & 15;

    const float* Cb = C + ((size_t)(b * N_ + r0)) * D_;
    const float* Qb = Q + (size_t)b * M_ * D_;

    __shared__ __align__(16) char uni[49152];
    __shared__ float sW1[D_], sW3[D_];
    __shared__ float sQlog[M_];
    __shared__ int   sQmask[M_];
    __shared__ float sClog[32];
    __shared__ float sRedR[64], sRedM[64], sRedS[64];

    char* sCwH = uni;
    char* sCwL = uni + 4096;
    char* sQH  = uni + 8192;
    char* sQL  = uni + 24576;
    char* sPt  = uni;
    char* sQtP = uni + 16384;

    for (int k = t; k < D_; k += 256) { sW1[k] = w1[k]; sW3[k] = w3[k]; }
    if (t < M_) { sQlog[t] = qlog[b * M_ + t]; sQmask[t] = q_mask[b * M_ + t]; }

    f32x4 acc[4] = {};
    float clog = 0.f;
    const int cr = t >> 3, ckq = t & 7;
    const int qj = t >> 1, qk0 = (t & 1) * 32;

    for (int kb = 0; kb < D_; kb += 64) {
        __syncthreads();
        {
            const float* p = Cb + (size_t)cr * D_ + kb + ckq * 8;
            float4 a  = *(const float4*)p;
            float4 bb = *(const float4*)(p + 4);
            float cc[8] = {a.x, a.y, a.z, a.w, bb.x, bb.y, bb.z, bb.w};
            bf16x8 hv, lv;
            int kk = kb + ckq * 8;
#pragma unroll
            for (int e = 0; e < 8; ++e) {
                clog += cc[e] * sW1[kk + e];
                unsigned short h, l;
                splitf(cc[e] * sW3[kk + e], h, l);
                hv[e] = (short)h; lv[e] = (short)l;
            }
            int pg = (ckq ^ (cr & 7)) * 16;
            *(bf16x8*)(sCwH + cr * 128 + pg) = hv;
            *(bf16x8*)(sCwL + cr * 128 + pg) = lv;
        }
        {
            const float* p = Qb + (size_t)qj * D_ + kb + qk0;
#pragma unroll
            for (int u = 0; u < 4; ++u) {
                float4 a  = *(const float4*)(p + u * 8);
                float4 bb = *(const float4*)(p + u * 8 + 4);
                float qq[8] = {a.x, a.y, a.z, a.w, bb.x, bb.y, bb.z, bb.w};
                bf16x8 hv, lv;
#pragma unroll
                for (int e = 0; e < 8; ++e) {
                    unsigned short h, l;
                    splitf(qq[e], h, l);
                    hv[e] = (short)h; lv[e] = (short)l;
                }
                int g  = (t & 1) * 4 + u;
                int pg = (g ^ (qj & 7)) * 16;
                *(bf16x8*)(sQH + qj * 128 + pg) = hv;
                *(bf16x8*)(sQL + qj * 128 + pg) = lv;
            }
        }
        __syncthreads();
        const int arow = rg * 16 + c15;
#pragma unroll
        for (int ks = 0; ks < 2; ++ks) {
            int g  = ks * 4 + q4;
            int pg = (g ^ (c15 & 7)) * 16;
            bf16x8 ah = *(const bf16x8*)(sCwH + arow * 128 + pg);
            bf16x8 al = *(const bf16x8*)(sCwL + arow * 128 + pg);
#pragma unroll
            for (int jt = 0; jt < 4; ++jt) {
                int jr = jh * 64 + jt * 16 + c15;
                bf16x8 bh = *(const bf16x8*)(sQH + jr * 128 + pg);
                bf16x8 bl = *(const bf16x8*)(sQL + jr * 128 + pg);
                acc[jt] = __builtin_amdgcn_mfma_f32_16x16x32_bf16(ah, bh, acc[jt], 0, 0, 0);
                acc[jt] = __builtin_amdgcn_mfma_f32_16x16x32_bf16(ah, bl, acc[jt], 0, 0, 0);
                acc[jt] = __builtin_amdgcn_mfma_f32_16x16x32_bf16(al, bh, acc[jt], 0, 0, 0);
            }
        }
    }

    clog += __shfl_xor(clog, 1); clog += __shfl_xor(clog, 2); clog += __shfl_xor(clog, 4);
    if ((t & 7) == 0) sClog[cr] = clog;
    __syncthreads();

    float qlg[4]; int qmv[4];
#pragma unroll
    for (int jt = 0; jt < 4; ++jt) {
        int j = jh * 64 + jt * 16 + c15;
        qlg[jt] = sQlog[j]; qmv[jt] = sQmask[j];
    }
    int cmv[4]; float clgr[4];
#pragma unroll
    for (int rr = 0; rr < 4; ++rr) {
        int row = rg * 16 + q4 * 4 + rr;
        cmv[rr]  = c_mask[b * N_ + r0 + row];
        clgr[rr] = sClog[row];
    }
    float mv[4][4], rmx[4], mmx[4];
#pragma unroll
    for (int rr = 0; rr < 4; ++rr) { rmx[rr] = -INFINITY; mmx[rr] = -INFINITY; }
#pragma unroll
    for (int jt = 0; jt < 4; ++jt)
#pragma unroll
        for (int rr = 0; rr < 4; ++rr) {
            float val = acc[jt][rr] + clgr[rr] + qlg[jt];
            float m   = (cmv[rr] | qmv[jt]) ? NEGV : val;
            mv[jt][rr] = m;
            rmx[rr] = fmaxf(rmx[rr], val);
            mmx[rr] = fmaxf(mmx[rr], m);
        }
#pragma unroll
    for (int rr = 0; rr < 4; ++rr)
#pragma unroll
        for (int off = 8; off; off >>= 1) {
            rmx[rr] = fmaxf(rmx[rr], __shfl_xor(rmx[rr], off));
            mmx[rr] = fmaxf(mmx[rr], __shfl_xor(mmx[rr], off));
        }
    if (c15 == 0) {
#pragma unroll
        for (int rr = 0; rr < 4; ++rr) {
            int row = rg * 16 + q4 * 4 + rr;
            sRedR[row * 2 + jh] = rmx[rr];
            sRedM[row * 2 + jh] = mmx[rr];
        }
    }
    __syncthreads();
    float Mm[4], sum[4];
#pragma unroll
    for (int rr = 0; rr < 4; ++rr) {
        int row = rg * 16 + q4 * 4 + rr;
        float Mraw = fmaxf(sRedR[row * 2], sRedR[row * 2 + 1]);
        Mm[rr] = fmaxf(sRedM[row * 2], sRedM[row * 2 + 1]);
        if (jh == 0 && c15 == 0) rowmax[b * N_ + r0 + row] = Mraw;
        sum[rr] = 0.f;
    }
    float p[4][4];
#pragma unroll
    for (int jt = 0; jt < 4; ++jt)
#pragma unroll
        for (int rr = 0; rr < 4; ++rr) {
            float e = __expf(mv[jt][rr] - Mm[rr]);
            p[jt][rr] = e; sum[rr] += e;
        }
#pragma unroll
    for (int rr = 0; rr < 4; ++rr) {
#pragma unroll
        for (int off = 8; off; off >>= 1) sum[rr] += __shfl_xor(sum[rr], off);
        if (c15 == 0) sRedS[(rg * 16 + q4 * 4 + rr) * 2 + jh] = sum[rr];
    }
    __syncthreads();
#pragma unroll
    for (int rr = 0; rr < 4; ++rr) {
        int row = rg * 16 + q4 * 4 + rr;
        float inv = 1.f / (sRedS[row * 2] + sRedS[row * 2 + 1]);
#pragma unroll
        for (int jt = 0; jt < 4; ++jt) {
            float P = p[jt][rr] * inv;
            unsigned short h, l; splitf(P, h, l);
            unsigned pk = ((unsigned)h << 16) | (unsigned)l;
            int j  = jh * 64 + jt * 16 + c15;
            int gu = j >> 2;
            *(unsigned*)(sPt + row * 512 + ((gu ^ (row & 7)) * 16) + (j & 3) * 4) = pk;
        }
    }

    const int pj = t >> 1, pdh = (t & 1) * 32;
    for (int d0 = 0; d0 < D_; d0 += 64) {
        __syncthreads();
        {
            const float* p = Qb + (size_t)pj * D_ + d0 + pdh;
            int gu = pj >> 2, joff = (pj & 3) * 4;
#pragma unroll
            for (int u = 0; u < 8; ++u) {
                float4 a = *(const float4*)(p + u * 4);
                float qq[4] = {a.x, a.y, a.z, a.w};
#pragma unroll
                for (int e = 0; e < 4; ++e) {
                    unsigned short h, l; splitf(qq[e], h, l);
                    int d = pdh + u * 4 + e;
                    *(unsigned*)(sQtP + d * 512 + ((gu ^ (d & 7)) * 16) + joff) =
                        ((unsigned)h << 16) | (unsigned)l;
                }
            }
        }
        __syncthreads();
        f32x4 acc2[2] = {};
        const int prow = rg * 16 + c15;
#pragma unroll
        for (int ks2 = 0; ks2 < 4; ++ks2) {
            int gu0 = ks2 * 8 + q4 * 2;
            u32x4 pa = *(const u32x4*)(sPt + prow * 512 + ((gu0 ^ (c15 & 7)) * 16));
            u32x4 pb = *(const u32x4*)(sPt + prow * 512 + (((gu0 + 1) ^ (c15 & 7)) * 16));
            bf16x8 phi, plo;
#pragma unroll
            for (int e = 0; e < 4; ++e) {
                phi[e]     = (short)(pa[e] >> 16); plo[e]     = (short)(pa[e] & 0xffffu);
                phi[e + 4] = (short)(pb[e] >> 16); plo[e + 4] = (short)(pb[e] & 0xffffu);
            }
#pragma unroll
            for (int dt = 0; dt < 2; ++dt) {
                int dr = jh * 32 + dt * 16 + c15;
                u32x4 qa = *(const u32x4*)(sQtP + dr * 512 + ((gu0 ^ (dr & 7)) * 16));
                u32x4 qb = *(const u32x4*)(sQtP + dr * 512 + (((gu0 + 1) ^ (dr & 7)) * 16));
                bf16x8 bh, bl;
#pragma unroll
                for (int e = 0; e < 4; ++e) {
                    bh[e]     = (short)(qa[e] >> 16); bl[e]     = (short)(qa[e] & 0xffffu);
                    bh[e + 4] = (short)(qb[e] >> 16); bl[e + 4] = (short)(qb[e] & 0xffffu);
                }
                acc2[dt] = __builtin_amdgcn_mfma_f32_16x16x32_bf16(phi, bh, acc2[dt], 0, 0, 0);
                acc2[dt] = __builtin_amdgcn_mfma_f32_16x16x32_bf16(phi, bl, acc2[dt], 0, 0, 0);
                acc2[dt] = __builtin_amdgcn_mfma_f32_16x16x32_bf16(plo, bh, acc2[dt], 0, 0, 0);
            }
        }
#pragma unroll
        for (int dt = 0; dt < 2; ++dt)
#pragma unroll
            for (int rr = 0; rr < 4; ++rr) {
                int row  = rg * 16 + q4 * 4 + rr;
                int dcol = d0 + jh * 32 + dt * 16 + c15;
                float a = acc2[dt][rr];
                float c = Cb[(size_t)row * D_ + dcol];
                size_t ob = (size_t)(b * N_ + r0 + row) * 3072;
                out[ob + dcol] = c;
                out[ob + 768 + dcol] = a;
                out[ob + 1536 + dcol] = c * a;
            }
    }
}

__global__ __launch_bounds__(256) void k_q2c(const float* __restrict__ rowmax,
                                             const int* __restrict__ c_mask,
                                             float* __restrict__ wq2c) {
    int b = blockIdx.x, t = threadIdx.x;
    __shared__ float red[8];
    float l[4];
#pragma unroll
    for (int u = 0; u < 4; ++u) {
        int i = t + u * 256;
        l[u] = (c_mask[b * N_ + i] != 0) ? NEGV : rowmax[b * N_ + i];
    }
    float mx = fmaxf(fmaxf(l[0], l[1]), fmaxf(l[2], l[3]));
#pragma unroll
    for (int off = 32; off; off >>= 1) mx = fmaxf(mx, __shfl_xor(mx, off));
    if ((t & 63) == 0) red[t >> 6] = mx;
    __syncthreads();
    mx = fmaxf(fmaxf(red[0], red[1]), fmaxf(red[2], red[3]));
    float e[4], s = 0.f;
#pragma unroll
    for (int u = 0; u < 4; ++u) { e[u] = __expf(l[u] - mx); s += e[u]; }
#pragma unroll
    for (int off = 32; off; off >>= 1) s += __shfl_xor(s, off);
    if ((t & 63) == 0) red[4 + (t >> 6)] = s;
    __syncthreads();
    s = red[4] + red[5] + red[6] + red[7];
    float inv = 1.f / s;
#pragma unroll
    for (int u = 0; u < 4; ++u) wq2c[b * N_ + t + u * 256] = e[u] * inv;
}

__global__ __launch_bounds__(256) void k_bctx(const float* __restrict__ C,
                                              const float* __restrict__ wq2c,
                                              float* __restrict__ Bctx) {
    int b  = blockIdx.x / 12;
    int c0 = (blockIdx.x % 12) * 64;
    int t  = threadIdx.x;
    int col = t & 63, ig = t >> 6;
    __shared__ float partl[4][64];
    const float* wb = wq2c + b * N_;
    const float* Cb = C + (size_t)b * N_ * D_;
    float s = 0.f;
    for (int i = ig * 256; i < ig * 256 + 256; ++i)
        s += wb[i] * Cb[(size_t)i * D_ + c0 + col];
    partl[ig][col] = s;
    __syncthreads();
    if (t < 64) Bctx[b * D_ + c0 + t] = partl[0][t] + partl[1][t] + partl[2][t] + partl[3][t];
}

__global__ __launch_bounds__(192) void k_final(const float* __restrict__ C,
                                               const float* __restrict__ Bctx,
                                               float* __restrict__ out) {
    int row = blockIdx.x;
    int b = row >> 10;
    int t = threadIdx.x;
    float4 c = *(const float4*)(C + (size_t)row * D_ + t * 4);
    float4 g = *(const float4*)(Bctx + (size_t)b * D_ + t * 4);
    *(float4*)(out + (size_t)row * 3072 + 2304 + t * 4) =
        make_float4(c.x * g.x, c.y * g.y, c.z * g.z, c.w * g.w);
}

extern "C" void kernel_launch(void* const* d_in, const int* in_sizes, int n_in,
                              void* d_out, int out_size, void* d_ws, size_t ws_size,
                              hipStream_t stream) {
    const float* C      = (const float*)d_in[0];
    const float* Q      = (const float*)d_in[1];
    const int*   c_mask = (const int*)d_in[2];
    const int*   q_mask = (const int*)d_in[3];
    const float* w1     = (const float*)d_in[4];
    const float* w2     = (const float*)d_in[5];
    const float* w3     = (const float*)d_in[6];
    float* out = (float*)d_out;
    char*  wsb = (char*)d_ws;

    float* qlogp = (float*)(wsb + OFF_QLOGP);
    float* part  = (float*)(wsb + OFF_PART);
    char*  pimg  = wsb + OFF_PIMG;

    if (ws_size >= WS_NEED) {
        char* qwh = wsb + OFF_QIMG;
        char* qwl = qwh + SZ_QIMG;
        char* qth = qwl + SZ_QIMG;
        char* qtl = qth + SZ_QIMG;
        k_prep2<<<B_ * NCH * 2, 256, 0, stream>>>(Q, w2, w3, qwh, qwl, qth, qtl, qlogp);
        const char *qwh_c = qwh, *qwl_c = qwl, *qth_c = qth, *qtl_c = qtl;
        void* args[11] = {(void*)&C, (void*)&c_mask, (void*)&q_mask, (void*)&w1,
                          (void*)&qlogp, (void*)&qwh_c, (void*)&qwl_c, (void*)&qth_c,
                          (void*)&qtl_c, (void*)&part, (void*)&out};
        hipError_t e = hipLaunchCooperativeKernel((void*)k_mainc, dim3(512), dim3(256),
                                                  args, 0, stream);
        if (e != hipSuccess) {
            k_main1<<<512, 256, 0, stream>>>(C, c_mask, q_mask, w1, qlogp, qwh, qwl, part, pimg);
            k_main2<<<512, 256, 0, stream>>>(C, part, qth, qtl, pimg, out);
        }
    } else {
        float* qlog   = (float*)(wsb + 0);
        float* rowmax = (float*)(wsb + 196608);
        float* wq2c   = (float*)(wsb + 262144);
        float* bctx   = (float*)(wsb + 327680);
        k_qlogit<<<512, 256, 0, stream>>>(Q, w2, qlog);
        k_main_fb<<<512, 256, 0, stream>>>(C, Q, c_mask, q_mask, w1, w3, qlog, rowmax, out);
        k_q2c<<<16, 256, 0, stream>>>(rowmax, c_mask, wq2c);
        k_bctx<<<192, 256, 0, stream>>>(C, wq2c, bctx);
        k_final<<<16384, 192, 0, stream>>>(C, bctx, out);
    }
}

// Round 12
// 102.391 us; speedup vs baseline: 2.1241x; 2.1241x over previous
//
#include <hip/hip_runtime.h>
#include <math.h>
#include <stdint.h>

#define NEGV -1e9f
typedef float f32x4 __attribute__((ext_vector_type(4)));
typedef short bf16x8 __attribute__((ext_vector_type(8)));
typedef unsigned int u32x4 __attribute__((ext_vector_type(4)));

constexpr int B_ = 16, N_ = 1024, M_ = 128, D_ = 768;
constexpr int NCH = 12;   // 768/64 chunks
constexpr int NQP = 24;   // qlogp partials per (b,j)

// ws layout (bytes):
constexpr size_t OFF_QLOGP = 0;          // f32[16*128*24] = 196608
constexpr size_t OFF_PART  = 196608;     // 512 slots * 4096 B -> 2293760
constexpr size_t OFF_PIMG  = 2293760;    // 512 * 16384 -> 10682368
constexpr size_t OFF_QIMG  = 10682368;   // QwH,QwL,QtH,QtL
constexpr size_t SZ_QIMG   = 3145728;
constexpr size_t WS_NEED   = OFF_QIMG + 4 * SZ_QIMG;  // ~23.3 MB
// R2-fallback aliases: qlog@0, rowmax@196608, wq2c@262144, bctx@327680

__device__ __forceinline__ unsigned short bf_rne(float x) {
    unsigned u = __float_as_uint(x);
    return (unsigned short)((u + 0x7fffu + ((u >> 16) & 1u)) >> 16);
}
__device__ __forceinline__ void splitf(float x, unsigned short& h, unsigned short& l) {
    unsigned short hb = bf_rne(x);
    float hf = __uint_as_float((unsigned)hb << 16);
    h = hb;
    l = bf_rne(x - hf);
}
__device__ __forceinline__ void gl_lds16(const void* g, void* l) {
    __builtin_amdgcn_global_load_lds(
        (const __attribute__((address_space(1))) void*)g,
        (__attribute__((address_space(3))) void*)l, 16, 0, 0);
}

// ---------------- k_prep2 (R11-verified): col-split (b, chunk, half) -> 384 blocks ----------------
__global__ __launch_bounds__(256) void k_prep2(const float* __restrict__ Q,
                                               const float* __restrict__ w2,
                                               const float* __restrict__ w3,
                                               char* __restrict__ qwh, char* __restrict__ qwl,
                                               char* __restrict__ qth, char* __restrict__ qtl,
                                               float* __restrict__ qlogp) {
    const int bi = blockIdx.x;
    const int b = bi / (NCH * 2), rem = bi % (NCH * 2);
    const int c = rem >> 1, half = rem & 1;
    const int t = threadIdx.x;
    __shared__ unsigned sT[128][33];
    __shared__ float sW2h[32], sW3h[32];
    if (t < 32) sW2h[t] = w2[c * 64 + half * 32 + t];
    else if (t < 64) sW3h[t - 32] = w3[c * 64 + half * 32 + (t - 32)];
    __syncthreads();
    const int j = t >> 1, h16 = t & 1;
    const float* src = Q + ((size_t)(b * M_ + j)) * D_ + c * 64 + half * 32 + h16 * 16;
    unsigned short hs[16], ls[16];
    float qsum = 0.f;
#pragma unroll
    for (int u = 0; u < 4; ++u) {
        float4 v = *(const float4*)(src + u * 4);
        float f[4] = {v.x, v.y, v.z, v.w};
#pragma unroll
        for (int e = 0; e < 4; ++e) {
            int idx = u * 4 + e;
            int lc  = h16 * 16 + idx;
            qsum += f[e] * sW2h[lc];
            unsigned short rh, rl; splitf(f[e], rh, rl);
            sT[j][lc] = ((unsigned)rh << 16) | (unsigned)rl;
            unsigned short h, l; splitf(f[e] * sW3h[lc], h, l);
            hs[idx] = h; ls[idx] = l;
        }
    }
    qsum += __shfl_xor(qsum, 1);
    if (h16 == 0) qlogp[(size_t)(b * M_ + j) * NQP + c * 2 + half] = qsum;
    size_t cb = ((size_t)(b * NCH + c)) * 16384;
    {
        int jh = j >> 6, jt = (j >> 4) & 3, c15j = j & 15;
#pragma unroll
        for (int u2 = 0; u2 < 2; ++u2) {
            int g = half * 4 + h16 * 2 + u2, ks = g >> 2, q4g = g & 3;
            int lane = q4g * 16 + c15j;
            bf16x8 hv, lv;
#pragma unroll
            for (int e = 0; e < 8; ++e) { hv[e] = (short)hs[u2 * 8 + e]; lv[e] = (short)ls[u2 * 8 + e]; }
            size_t off = cb + (size_t)((((jh * 2 + ks) * 4 + jt) * 64 + lane) * 16);
            *(bf16x8*)(qwh + off) = hv;
            *(bf16x8*)(qwl + off) = lv;
        }
    }
    __syncthreads();
#pragma unroll
    for (int u = 0; u < 2; ++u) {
        int id = t * 2 + u;
        int dd_loc = id >> 4, gj = id & 15;
        int dt = dd_loc >> 4, c15q = dd_loc & 15;
        int ks2 = gj >> 2, q4g = gj & 3;
        int lane = q4g * 16 + c15q;
        bf16x8 hv, lv;
#pragma unroll
        for (int e = 0; e < 8; ++e) {
            unsigned p = sT[gj * 8 + e][dd_loc];
            hv[e] = (short)(p >> 16); lv[e] = (short)(p & 0xffffu);
        }
        size_t off = cb + (size_t)((((half * 4 + ks2) * 2 + dt) * 64 + lane) * 16);
        *(bf16x8*)(qth + off) = hv;
        *(bf16x8*)(qtl + off) = lv;
    }
}

// ---------------- k_main1 (R10-verified body, qlogp-24): phases 1+2 + partials + P dump ----------------
__global__ __launch_bounds__(256, 3) void k_main1(const float* __restrict__ C,
                                                  const int* __restrict__ c_mask,
                                                  const int* __restrict__ q_mask,
                                                  const float* __restrict__ w1,
                                                  const float* __restrict__ qlogp,
                                                  const char* __restrict__ qwh,
                                                  const char* __restrict__ qwl,
                                                  float* __restrict__ part,
                                                  char* __restrict__ pimg) {
    const int bid = (blockIdx.x & 7) * 64 + (blockIdx.x >> 3);  // XCD-chunked, bijective
    const int b  = bid >> 5;
    const int r0 = (bid & 31) * 32;
    const int t  = threadIdx.x;
    const int wv = t >> 6, lane = t & 63;
    const int rg = wv >> 1, jh = wv & 1;
    const int q4 = lane >> 4, c15 = t & 15;

    const float* Cb = C + ((size_t)(b * N_ + r0)) * D_;

    __shared__ __align__(16) char uni[49152];
    __shared__ float sQlog[M_];
    __shared__ int   sQmask[M_];
    __shared__ float sClog[32], sMraw[32], sMl[32], sWr[32];
    __shared__ float sRedR[64], sRedM[64], sRedS[64];

    char* sQH = uni;
    char* sQL = uni + 16384;
    char* sPH = uni + 32768;
    char* sPL = uni + 40960;
    float* sW1 = (float*)(uni + 32768);  // aliases sPH; dead before P store

    for (int k = t; k < D_; k += 256) sW1[k] = w1[k];
    if (t < M_) {
        const float* qp = qlogp + (size_t)(b * M_ + t) * NQP;
        float s = 0.f;
#pragma unroll
        for (int u = 0; u < 6; ++u) {
            float4 v = ((const float4*)qp)[u];
            s += (v.x + v.y) + (v.z + v.w);
        }
        sQlog[t] = s;
        sQmask[t] = q_mask[b * M_ + t];
    }
    __syncthreads();

    f32x4 acc[4] = {};
    float clogp = 0.f;
    const int arow = rg * 16 + c15;
    const float* CbA = Cb + (size_t)arow * D_;
    const size_t qcb = (size_t)(b * NCH) * 16384;

    for (int kidx = 0; kidx < NCH; ++kidx) {
        __syncthreads();
        {
            size_t gb = qcb + (size_t)kidx * 16384;
#pragma unroll
            for (int it = 0; it < 4; ++it) {
                int qo = it * 4096 + wv * 1024;
                gl_lds16(qwh + gb + qo + lane * 16, sQH + qo);
                gl_lds16(qwl + gb + qo + lane * 16, sQL + qo);
            }
        }
        bf16x8 ah[2], al[2];
        const int kb = kidx * 64;
#pragma unroll
        for (int ks = 0; ks < 2; ++ks) {
            const int k0 = kb + (ks * 4 + q4) * 8;
            float4 ca  = *(const float4*)(CbA + k0);
            float4 cb2 = *(const float4*)(CbA + k0 + 4);
            float cc[8] = {ca.x, ca.y, ca.z, ca.w, cb2.x, cb2.y, cb2.z, cb2.w};
#pragma unroll
            for (int e = 0; e < 8; ++e) {
                clogp += cc[e] * sW1[k0 + e];
                unsigned short h, l; splitf(cc[e], h, l);
                ah[ks][e] = (short)h; al[ks][e] = (short)l;
            }
        }
        __syncthreads();
#pragma unroll
        for (int ks = 0; ks < 2; ++ks) {
#pragma unroll
            for (int jt = 0; jt < 4; ++jt) {
                int fo = (((jh * 2 + ks) * 4 + jt) * 64 + lane) * 16;
                bf16x8 bh = *(const bf16x8*)(sQH + fo);
                bf16x8 bl = *(const bf16x8*)(sQL + fo);
                acc[jt] = __builtin_amdgcn_mfma_f32_16x16x32_bf16(ah[ks], bh, acc[jt], 0, 0, 0);
                acc[jt] = __builtin_amdgcn_mfma_f32_16x16x32_bf16(ah[ks], bl, acc[jt], 0, 0, 0);
                acc[jt] = __builtin_amdgcn_mfma_f32_16x16x32_bf16(al[ks], bh, acc[jt], 0, 0, 0);
            }
        }
    }
    clogp += __shfl_xor(clogp, 16);
    clogp += __shfl_xor(clogp, 32);
    if (jh == 0 && q4 == 0) sClog[arow] = clogp;
    __syncthreads();

    float qlg[4]; int qmv[4];
#pragma unroll
    for (int jt = 0; jt < 4; ++jt) {
        int j = jh * 64 + jt * 16 + c15;
        qlg[jt] = sQlog[j]; qmv[jt] = sQmask[j];
    }
    int cmv[4]; float clgr[4];
#pragma unroll
    for (int rr = 0; rr < 4; ++rr) {
        int row = rg * 16 + q4 * 4 + rr;
        cmv[rr]  = c_mask[b * N_ + r0 + row];
        clgr[rr] = sClog[row];
    }
    float mv[4][4], rmx[4], mmx[4];
#pragma unroll
    for (int rr = 0; rr < 4; ++rr) { rmx[rr] = -INFINITY; mmx[rr] = -INFINITY; }
#pragma unroll
    for (int jt = 0; jt < 4; ++jt)
#pragma unroll
        for (int rr = 0; rr < 4; ++rr) {
            float val = acc[jt][rr] + clgr[rr] + qlg[jt];
            float m   = (cmv[rr] | qmv[jt]) ? NEGV : val;
            mv[jt][rr] = m;
            rmx[rr] = fmaxf(rmx[rr], val);
            mmx[rr] = fmaxf(mmx[rr], m);
        }
#pragma unroll
    for (int rr = 0; rr < 4; ++rr)
#pragma unroll
        for (int off = 8; off; off >>= 1) {
            rmx[rr] = fmaxf(rmx[rr], __shfl_xor(rmx[rr], off));
            mmx[rr] = fmaxf(mmx[rr], __shfl_xor(mmx[rr], off));
        }
    if (c15 == 0) {
#pragma unroll
        for (int rr = 0; rr < 4; ++rr) {
            int row = rg * 16 + q4 * 4 + rr;
            sRedR[row * 2 + jh] = rmx[rr];
            sRedM[row * 2 + jh] = mmx[rr];
        }
    }
    __syncthreads();
    float Mm[4], sum[4];
#pragma unroll
    for (int rr = 0; rr < 4; ++rr) {
        int row = rg * 16 + q4 * 4 + rr;
        float Mraw = fmaxf(sRedR[row * 2], sRedR[row * 2 + 1]);
        Mm[rr] = fmaxf(sRedM[row * 2], sRedM[row * 2 + 1]);
        if (jh == 0 && c15 == 0) sMraw[row] = Mraw;
        sum[rr] = 0.f;
    }
    float p[4][4];
#pragma unroll
    for (int jt = 0; jt < 4; ++jt)
#pragma unroll
        for (int rr = 0; rr < 4; ++rr) {
            float e = __expf(mv[jt][rr] - Mm[rr]);
            p[jt][rr] = e; sum[rr] += e;
        }
#pragma unroll
    for (int rr = 0; rr < 4; ++rr) {
#pragma unroll
        for (int off = 8; off; off >>= 1) sum[rr] += __shfl_xor(sum[rr], off);
        if (c15 == 0) sRedS[(rg * 16 + q4 * 4 + rr) * 2 + jh] = sum[rr];
    }
    __syncthreads();   // sW1 (alias sPH) dead past here
#pragma unroll
    for (int rr = 0; rr < 4; ++rr) {
        int row = rg * 16 + q4 * 4 + rr;
        float inv = 1.f / (sRedS[row * 2] + sRedS[row * 2 + 1]);
#pragma unroll
        for (int jt = 0; jt < 4; ++jt) {
            float P = p[jt][rr] * inv;
            unsigned short h, l; splitf(P, h, l);
            int j = jh * 64 + jt * 16 + c15;
            int addr = row * 256 + (((j >> 3) ^ (row & 7)) * 16) + (j & 7) * 2;
            *(short*)(sPH + addr) = (short)h;
            *(short*)(sPL + addr) = (short)l;
        }
    }
    __syncthreads();

    if (t < 32) sMl[t] = (c_mask[b * N_ + r0 + t] != 0) ? NEGV : sMraw[t];
    __syncthreads();
    float lm = -INFINITY;
#pragma unroll
    for (int r = 0; r < 32; ++r) lm = fmaxf(lm, sMl[r]);
    if (t < 32) sWr[t] = __expf(sMl[t] - lm);
    __syncthreads();
    float den = 0.f;
#pragma unroll
    for (int r = 0; r < 32; ++r) den += sWr[r];
    {
        float a0 = 0.f, a1 = 0.f, a2 = 0.f;
        for (int r = 0; r < 32; ++r) {
            float w = sWr[r];
            if (w != 0.f) {
                const float* cr = Cb + (size_t)r * D_;
                a0 += w * cr[t]; a1 += w * cr[t + 256]; a2 += w * cr[t + 512];
            }
        }
        float* slot = part + (size_t)bid * 1024;
        slot[2 + t] = a0; slot[2 + t + 256] = a1; slot[2 + t + 512] = a2;
        if (t == 0) { slot[0] = lm; slot[1] = den; }
    }
#pragma unroll
    for (int i = 0; i < 2; ++i) {
        *(u32x4*)(pimg + (size_t)bid * 16384 + t * 32 + i * 16) =
            *(const u32x4*)(sPH + t * 32 + i * 16);
        *(u32x4*)(pimg + (size_t)bid * 16384 + 8192 + t * 32 + i * 16) =
            *(const u32x4*)(sPL + t * 32 + i * 16);
    }
}

// ---------------- k_main2: inline combine + phase 3 + transposed float4 epilogue ----------------
__global__ __launch_bounds__(256, 3) void k_main2(const float* __restrict__ C,
                                                  const float* __restrict__ part,
                                                  const char* __restrict__ qth,
                                                  const char* __restrict__ qtl,
                                                  const char* __restrict__ pimg,
                                                  float* __restrict__ out) {
    const int bid = (blockIdx.x & 7) * 64 + (blockIdx.x >> 3);
    const int b  = bid >> 5;
    const int r0 = (bid & 31) * 32;
    const int t  = threadIdx.x;
    const int wv = t >> 6, lane = t & 63;
    const int rg = wv >> 1, jh = wv & 1;
    const int q4 = lane >> 4, c15 = t & 15;

    const float* Cb = C + ((size_t)(b * N_ + r0)) * D_;

    __shared__ __align__(16) char uni[49152];
    __shared__ __align__(16) float sBctx[D_];
    __shared__ float sLm[32], sDen[32], sSc[32];
    char* sQtH = uni;
    char* sQtL = uni + 16384;
    char* sPH  = uni + 32768;
    char* sPL  = uni + 40960;

    {   // load P image (async)
        const char* ps = pimg + (size_t)bid * 16384;
#pragma unroll
        for (int it = 0; it < 2; ++it) {
            int off = it * 4096 + wv * 1024;
            gl_lds16(ps + off + lane * 16, sPH + off);
            gl_lds16(ps + 8192 + off + lane * 16, sPL + off);
        }
    }
    if (t < 32) {
        const float* s = part + (size_t)(b * 32 + t) * 1024;
        sLm[t] = s[0]; sDen[t] = s[1];
    }
    __syncthreads();
    {
        float gm = -INFINITY;
#pragma unroll
        for (int r = 0; r < 32; ++r) gm = fmaxf(gm, sLm[r]);
        if (t < 32) sSc[t] = __expf(sLm[t] - gm);
        __syncthreads();
        float Ds = 0.f;
#pragma unroll
        for (int r = 0; r < 32; ++r) Ds += sDen[r] * sSc[r];
        float inv = 1.f / Ds;
#pragma unroll
        for (int u = 0; u < 3; ++u) {
            int col = t + u * 256;
            float a = 0.f;
            for (int rt = 0; rt < 32; ++rt)
                a += sSc[rt] * part[(size_t)(b * 32 + rt) * 1024 + 2 + col];
            sBctx[col] = a * inv;
        }
    }
    __syncthreads();

    bf16x8 pah[4], pal[4];
    const int prow = rg * 16 + c15;
#pragma unroll
    for (int ks2 = 0; ks2 < 4; ++ks2) {
        int gja = ks2 * 4 + q4;
        int pgp = (gja ^ (prow & 7)) * 16;
        pah[ks2] = *(const bf16x8*)(sPH + prow * 256 + pgp);
        pal[ks2] = *(const bf16x8*)(sPL + prow * 256 + pgp);
    }

    const int trow = rg * 16 + q4 * 4 + (c15 & 3);      // post-transpose row
    const int tg4  = (c15 >> 2) * 4;                    // post-transpose col offset
    const int a2   = t & 3;
    const size_t qcb = (size_t)(b * NCH) * 16384;

    for (int dc = 0; dc < NCH; ++dc) {
        __syncthreads();
        {
            size_t gb = qcb + (size_t)dc * 16384;
#pragma unroll
            for (int it = 0; it < 4; ++it) {
                int qo = it * 4096 + wv * 1024;
                gl_lds16(qth + gb + qo + lane * 16, sQtH + qo);
                gl_lds16(qtl + gb + qo + lane * 16, sQtL + qo);
            }
        }
        // prefetch transposed-layout C rows + bctx while staging drains
        float4 cpre[2], gpre[2];
#pragma unroll
        for (int dt = 0; dt < 2; ++dt) {
            int col4 = dc * 64 + jh * 32 + dt * 16 + tg4;
            cpre[dt] = *(const float4*)(Cb + (size_t)trow * D_ + col4);
            gpre[dt] = *(const float4*)&sBctx[col4];
        }
        __syncthreads();
        f32x4 acc2[2] = {};
#pragma unroll
        for (int ks2 = 0; ks2 < 4; ++ks2) {
#pragma unroll
            for (int dt = 0; dt < 2; ++dt) {
                int fo = (((jh * 4 + ks2) * 2 + dt) * 64 + lane) * 16;
                bf16x8 bh = *(const bf16x8*)(sQtH + fo);
                bf16x8 bl = *(const bf16x8*)(sQtL + fo);
                acc2[dt] = __builtin_amdgcn_mfma_f32_16x16x32_bf16(pah[ks2], bh, acc2[dt], 0, 0, 0);
                acc2[dt] = __builtin_amdgcn_mfma_f32_16x16x32_bf16(pah[ks2], bl, acc2[dt], 0, 0, 0);
                acc2[dt] = __builtin_amdgcn_mfma_f32_16x16x32_bf16(pal[ks2], bh, acc2[dt], 0, 0, 0);
            }
        }
#pragma unroll
        for (int dt = 0; dt < 2; ++dt) {
            // 4x4 transpose within lane groups (bits 0-1 of lane)
            float v0 = acc2[dt][0], v1 = acc2[dt][1], v2 = acc2[dt][2], v3 = acc2[dt][3];
            {
                float t0 = __shfl_xor(v1, 1), t1 = __shfl_xor(v0, 1);
                float t2 = __shfl_xor(v3, 1), t3 = __shfl_xor(v2, 1);
                if (a2 & 1) { v0 = t0; v2 = t2; } else { v1 = t1; v3 = t3; }
            }
            {
                float t0 = __shfl_xor(v2, 2), t1 = __shfl_xor(v3, 2);
                float t2 = __shfl_xor(v0, 2), t3 = __shfl_xor(v1, 2);
                if (a2 & 2) { v0 = t0; v1 = t1; } else { v2 = t2; v3 = t3; }
            }
            int col4 = dc * 64 + jh * 32 + dt * 16 + tg4;
            float4 cv = cpre[dt], gv = gpre[dt];
            size_t ob = (size_t)(b * N_ + r0 + trow) * 3072;
            *(float4*)(out + ob + col4)        = cv;
            *(float4*)(out + ob + 768 + col4)  = make_float4(v0, v1, v2, v3);
            *(float4*)(out + ob + 1536 + col4) = make_float4(cv.x * v0, cv.y * v1, cv.z * v2, cv.w * v3);
            *(float4*)(out + ob + 2304 + col4) = make_float4(cv.x * gv.x, cv.y * gv.y, cv.z * gv.z, cv.w * gv.w);
        }
    }
}

// ---------------- R2-proven full-fallback chain ----------------
__global__ __launch_bounds__(256) void k_qlogit(const float* __restrict__ Q,
                                                const float* __restrict__ w2,
                                                float* __restrict__ qlog) {
    int idx  = blockIdx.x * 4 + (threadIdx.x >> 6);
    int lane = threadIdx.x & 63;
    const float* q = Q + (size_t)idx * D_;
    float s = 0.f;
    for (int k = lane; k < D_; k += 64) s += q[k] * w2[k];
#pragma unroll
    for (int off = 32; off; off >>= 1) s += __shfl_xor(s, off);
    if (lane == 0) qlog[idx] = s;
}

__global__ __launch_bounds__(256, 2) void k_main_fb(const float* __restrict__ C,
                                                    const float* __restrict__ Q,
                                                    const int* __restrict__ c_mask,
                                                    const int* __restrict__ q_mask,
                                                    const float* __restrict__ w1,
                                                    const float* __restrict__ w3,
                                                    const float* __restrict__ qlog,
                                                    float* __restrict__ rowmax,
                                                    float* __restrict__ out) {
    const int bid = (blockIdx.x & 7) * 64 + (blockIdx.x >> 3);
    const int b  = bid >> 5;
    const int r0 = (bid & 31) * 32;
    const int t  = threadIdx.x;
    const int wv = t >> 6;
    const int rg = wv >> 1, jh = wv & 1;
    const int q4 = (t & 63) >> 4, c15 = t & 15;

    const float* Cb = C + ((size_t)(b * N_ + r0)) * D_;
    const float* Qb = Q + (size_t)b * M_ * D_;

    __shared__ __align__(16) char uni[49152];
    __shared__ float sW1[D_], sW3[D_];
    __shared__ float sQlog[M_];
    __shared__ int   sQmask[M_];
    __shared__ float sClog[32];
    __shared__ float sRedR[64], sRedM[64], sRedS[64];

    char* sCwH = uni;
    char* sCwL = uni + 4096;
    char* sQH  = uni + 8192;
    char* sQL  = uni + 24576;
    char* sPt  = uni;
    char* sQtP = uni + 16384;

    for (int k = t; k < D_; k += 256) { sW1[k] = w1[k]; sW3[k] = w3[k]; }
    if (t < M_) { sQlog[t] = qlog[b * M_ + t]; sQmask[t] = q_mask[b * M_ + t]; }

    f32x4 acc[4] = {};
    float clog = 0.f;
    const int cr = t >> 3, ckq = t & 7;
    const int qj = t >> 1, qk0 = (t & 1) * 32;

    for (int kb = 0; kb < D_; kb += 64) {
        __syncthreads();
        {
            const float* p = Cb + (size_t)cr * D_ + kb + ckq * 8;
            float4 a  = *(const float4*)p;
            float4 bb = *(const float4*)(p + 4);
            float cc[8] = {a.x, a.y, a.z, a.w, bb.x, bb.y, bb.z, bb.w};
            bf16x8 hv, lv;
            int kk = kb + ckq * 8;
#pragma unroll
            for (int e = 0; e < 8; ++e) {
                clog += cc[e] * sW1[kk + e];
                unsigned short h, l;
                splitf(cc[e] * sW3[kk + e], h, l);
                hv[e] = (short)h; lv[e] = (short)l;
            }
            int pg = (ckq ^ (cr & 7)) * 16;
            *(bf16x8*)(sCwH + cr * 128 + pg) = hv;
            *(bf16x8*)(sCwL + cr * 128 + pg) = lv;
        }
        {
            const float* p = Qb + (size_t)qj * D_ + kb + qk0;
#pragma unroll
            for (int u = 0; u < 4; ++u) {
                float4 a  = *(const float4*)(p + u * 8);
                float4 bb = *(const float4*)(p + u * 8 + 4);
                float qq[8] = {a.x, a.y, a.z, a.w, bb.x, bb.y, bb.z, bb.w};
                bf16x8 hv, lv;
#pragma unroll
                for (int e = 0; e < 8; ++e) {
                    unsigned short h, l;
                    splitf(qq[e], h, l);
                    hv[e] = (short)h; lv[e] = (short)l;
                }
                int g  = (t & 1) * 4 + u;
                int pg = (g ^ (qj & 7)) * 16;
                *(bf16x8*)(sQH + qj * 128 + pg) = hv;
                *(bf16x8*)(sQL + qj * 128 + pg) = lv;
            }
        }
        __syncthreads();
        const int arow = rg * 16 + c15;
#pragma unroll
        for (int ks = 0; ks < 2; ++ks) {
            int g  = ks * 4 + q4;
            int pg = (g ^ (c15 & 7)) * 16;
            bf16x8 ah = *(const bf16x8*)(sCwH + arow * 128 + pg);
            bf16x8 al = *(const bf16x8*)(sCwL + arow * 128 + pg);
#pragma unroll
            for (int jt = 0; jt < 4; ++jt) {
                int jr = jh * 64 + jt * 16 + c15;
                bf16x8 bh = *(const bf16x8*)(sQH + jr * 128 + pg);
                bf16x8 bl = *(const bf16x8*)(sQL + jr * 128 + pg);
                acc[jt] = __builtin_amdgcn_mfma_f32_16x16x32_bf16(ah, bh, acc[jt], 0, 0, 0);
                acc[jt] = __builtin_amdgcn_mfma_f32_16x16x32_bf16(ah, bl, acc[jt], 0, 0, 0);
                acc[jt] = __builtin_amdgcn_mfma_f32_16x16x32_bf16(al, bh, acc[jt], 0, 0, 0);
            }
        }
    }

    clog += __shfl_xor(clog, 1); clog += __shfl_xor(clog, 2); clog += __shfl_xor(clog, 4);
    if ((t & 7) == 0) sClog[cr] = clog;
    __syncthreads();

    float qlg[4]; int qmv[4];
#pragma unroll
    for (int jt = 0; jt < 4; ++jt) {
        int j = jh * 64 + jt * 16 + c15;
        qlg[jt] = sQlog[j]; qmv[jt] = sQmask[j];
    }
    int cmv[4]; float clgr[4];
#pragma unroll
    for (int rr = 0; rr < 4; ++rr) {
        int row = rg * 16 + q4 * 4 + rr;
        cmv[rr]  = c_mask[b * N_ + r0 + row];
        clgr[rr] = sClog[row];
    }
    float mv[4][4], rmx[4], mmx[4];
#pragma unroll
    for (int rr = 0; rr < 4; ++rr) { rmx[rr] = -INFINITY; mmx[rr] = -INFINITY; }
#pragma unroll
    for (int jt = 0; jt < 4; ++jt)
#pragma unroll
        for (int rr = 0; rr < 4; ++rr) {
            float val = acc[jt][rr] + clgr[rr] + qlg[jt];
            float m   = (cmv[rr] | qmv[jt]) ? NEGV : val;
            mv[jt][rr] = m;
            rmx[rr] = fmaxf(rmx[rr], val);
            mmx[rr] = fmaxf(mmx[rr], m);
        }
#pragma unroll
    for (int rr = 0; rr < 4; ++rr)
#pragma unroll
        for (int off = 8; off; off >>= 1) {
            rmx[rr] = fmaxf(rmx[rr], __shfl_xor(rmx[rr], off));
            mmx[rr] = fmaxf(mmx[rr], __shfl_xor(mmx[rr], off));
        }
    if (c15 == 0) {
#pragma unroll
        for (int rr = 0; rr < 4; ++rr) {
            int row = rg * 16 + q4 * 4 + rr;
            sRedR[row * 2 + jh] = rmx[rr];
            sRedM[row * 2 + jh] = mmx[rr];
        }
    }
    __syncthreads();
    float Mm[4], sum[4];
#pragma unroll
    for (int rr = 0; rr < 4; ++rr) {
        int row = rg * 16 + q4 * 4 + rr;
        float Mraw = fmaxf(sRedR[row * 2], sRedR[row * 2 + 1]);
        Mm[rr] = fmaxf(sRedM[row * 2], sRedM[row * 2 + 1]);
        if (jh == 0 && c15 == 0) rowmax[b * N_ + r0 + row] = Mraw;
        sum[rr] = 0.f;
    }
    float p[4][4];
#pragma unroll
    for (int jt = 0; jt < 4; ++jt)
#pragma unroll
        for (int rr = 0; rr < 4; ++rr) {
            float e = __expf(mv[jt][rr] - Mm[rr]);
            p[jt][rr] = e; sum[rr] += e;
        }
#pragma unroll
    for (int rr = 0; rr < 4; ++rr) {
#pragma unroll
        for (int off = 8; off; off >>= 1) sum[rr] += __shfl_xor(sum[rr], off);
        if (c15 == 0) sRedS[(rg * 16 + q4 * 4 + rr) * 2 + jh] = sum[rr];
    }
    __syncthreads();
#pragma unroll
    for (int rr = 0; rr < 4; ++rr) {
        int row = rg * 16 + q4 * 4 + rr;
        float inv = 1.f / (sRedS[row * 2] + sRedS[row * 2 + 1]);
#pragma unroll
        for (int jt = 0; jt < 4; ++jt) {
            float P = p[jt][rr] * inv;
            unsigned short h, l; splitf(P, h, l);
            unsigned pk = ((unsigned)h << 16) | (unsigned)l;
            int j  = jh * 64 + jt * 16 + c15;
            int gu = j >> 2;
            *(unsigned*)(sPt + row * 512 + ((gu ^ (row & 7)) * 16) + (j & 3) * 4) = pk;
        }
    }

    const int pj = t >> 1, pdh = (t & 1) * 32;
    for (int d0 = 0; d0 < D_; d0 += 64) {
        __syncthreads();
        {
            const float* p = Qb + (size_t)pj * D_ + d0 + pdh;
            int gu = pj >> 2, joff = (pj & 3) * 4;
#pragma unroll
            for (int u = 0; u < 8; ++u) {
                float4 a = *(const float4*)(p + u * 4);
                float qq[4] = {a.x, a.y, a.z, a.w};
#pragma unroll
                for (int e = 0; e < 4; ++e) {
                    unsigned short h, l; splitf(qq[e], h, l);
                    int d = pdh + u * 4 + e;
                    *(unsigned*)(sQtP + d * 512 + ((gu ^ (d & 7)) * 16) + joff) =
                        ((unsigned)h << 16) | (unsigned)l;
                }
            }
        }
        __syncthreads();
        f32x4 acc2[2] = {};
        const int prow = rg * 16 + c15;
#pragma unroll
        for (int ks2 = 0; ks2 < 4; ++ks2) {
            int gu0 = ks2 * 8 + q4 * 2;
            u32x4 pa = *(const u32x4*)(sPt + prow * 512 + ((gu0 ^ (c15 & 7)) * 16));
            u32x4 pb = *(const u32x4*)(sPt + prow * 512 + (((gu0 + 1) ^ (c15 & 7)) * 16));
            bf16x8 phi, plo;
#pragma unroll
            for (int e = 0; e < 4; ++e) {
                phi[e]     = (short)(pa[e] >> 16); plo[e]     = (short)(pa[e] & 0xffffu);
                phi[e + 4] = (short)(pb[e] >> 16); plo[e + 4] = (short)(pb[e] & 0xffffu);
            }
#pragma unroll
            for (int dt = 0; dt < 2; ++dt) {
                int dr = jh * 32 + dt * 16 + c15;
                u32x4 qa = *(const u32x4*)(sQtP + dr * 512 + ((gu0 ^ (dr & 7)) * 16));
                u32x4 qb = *(const u32x4*)(sQtP + dr * 512 + (((gu0 + 1) ^ (dr & 7)) * 16));
                bf16x8 bh, bl;
#pragma unroll
                for (int e = 0; e < 4; ++e) {
                    bh[e]     = (short)(qa[e] >> 16); bl[e]     = (short)(qa[e] & 0xffffu);
                    bh[e + 4] = (short)(qb[e] >> 16); bl[e + 4] = (short)(qb[e] & 0xffffu);
                }
                acc2[dt] = __builtin_amdgcn_mfma_f32_16x16x32_bf16(phi, bh, acc2[dt], 0, 0, 0);
                acc2[dt] = __builtin_amdgcn_mfma_f32_16x16x32_bf16(phi, bl, acc2[dt], 0, 0, 0);
                acc2[dt] = __builtin_amdgcn_mfma_f32_16x16x32_bf16(plo, bh, acc2[dt], 0, 0, 0);
            }
        }
#pragma unroll
        for (int dt = 0; dt < 2; ++dt)
#pragma unroll
            for (int rr = 0; rr < 4; ++rr) {
                int row  = rg * 16 + q4 * 4 + rr;
                int dcol = d0 + jh * 32 + dt * 16 + c15;
                float a = acc2[dt][rr];
                float c = Cb[(size_t)row * D_ + dcol];
                size_t ob = (size_t)(b * N_ + r0 + row) * 3072;
                out[ob + dcol] = c;
                out[ob + 768 + dcol] = a;
                out[ob + 1536 + dcol] = c * a;
            }
    }
}

__global__ __launch_bounds__(256) void k_q2c(const float* __restrict__ rowmax,
                                             const int* __restrict__ c_mask,
                                             float* __restrict__ wq2c) {
    int b = blockIdx.x, t = threadIdx.x;
    __shared__ float red[8];
    float l[4];
#pragma unroll
    for (int u = 0; u < 4; ++u) {
        int i = t + u * 256;
        l[u] = (c_mask[b * N_ + i] != 0) ? NEGV : rowmax[b * N_ + i];
    }
    float mx = fmaxf(fmaxf(l[0], l[1]), fmaxf(l[2], l[3]));
#pragma unroll
    for (int off = 32; off; off >>= 1) mx = fmaxf(mx, __shfl_xor(mx, off));
    if ((t & 63) == 0) red[t >> 6] = mx;
    __syncthreads();
    mx = fmaxf(fmaxf(red[0], red[1]), fmaxf(red[2], red[3]));
    float e[4], s = 0.f;
#pragma unroll
    for (int u = 0; u < 4; ++u) { e[u] = __expf(l[u] - mx); s += e[u]; }
#pragma unroll
    for (int off = 32; off; off >>= 1) s += __shfl_xor(s, off);
    if ((t & 63) == 0) red[4 + (t >> 6)] = s;
    __syncthreads();
    s = red[4] + red[5] + red[6] + red[7];
    float inv = 1.f / s;
#pragma unroll
    for (int u = 0; u < 4; ++u) wq2c[b * N_ + t + u * 256] = e[u] * inv;
}

__global__ __launch_bounds__(256) void k_bctx(const float* __restrict__ C,
                                              const float* __restrict__ wq2c,
                                              float* __restrict__ Bctx) {
    int b  = blockIdx.x / 12;
    int c0 = (blockIdx.x % 12) * 64;
    int t  = threadIdx.x;
    int col = t & 63, ig = t >> 6;
    __shared__ float partl[4][64];
    const float* wb = wq2c + b * N_;
    const float* Cb = C + (size_t)b * N_ * D_;
    float s = 0.f;
    for (int i = ig * 256; i < ig * 256 + 256; ++i)
        s += wb[i] * Cb[(size_t)i * D_ + c0 + col];
    partl[ig][col] = s;
    __syncthreads();
    if (t < 64) Bctx[b * D_ + c0 + t] = partl[0][t] + partl[1][t] + partl[2][t] + partl[3][t];
}

__global__ __launch_bounds__(192) void k_final(const float* __restrict__ C,
                                               const float* __restrict__ Bctx,
                                               float* __restrict__ out) {
    int row = blockIdx.x;
    int b = row >> 10;
    int t = threadIdx.x;
    float4 c = *(const float4*)(C + (size_t)row * D_ + t * 4);
    float4 g = *(const float4*)(Bctx + (size_t)b * D_ + t * 4);
    *(float4*)(out + (size_t)row * 3072 + 2304 + t * 4) =
        make_float4(c.x * g.x, c.y * g.y, c.z * g.z, c.w * g.w);
}

extern "C" void kernel_launch(void* const* d_in, const int* in_sizes, int n_in,
                              void* d_out, int out_size, void* d_ws, size_t ws_size,
                              hipStream_t stream) {
    const float* C      = (const float*)d_in[0];
    const float* Q      = (const float*)d_in[1];
    const int*   c_mask = (const int*)d_in[2];
    const int*   q_mask = (const int*)d_in[3];
    const float* w1     = (const float*)d_in[4];
    const float* w2     = (const float*)d_in[5];
    const float* w3     = (const float*)d_in[6];
    float* out = (float*)d_out;
    char*  wsb = (char*)d_ws;

    float* qlogp = (float*)(wsb + OFF_QLOGP);
    float* part  = (float*)(wsb + OFF_PART);
    char*  pimg  = wsb + OFF_PIMG;

    if (ws_size >= WS_NEED) {
        char* qwh = wsb + OFF_QIMG;
        char* qwl = qwh + SZ_QIMG;
        char* qth = qwl + SZ_QIMG;
        char* qtl = qth + SZ_QIMG;
        k_prep2<<<B_ * NCH * 2, 256, 0, stream>>>(Q, w2, w3, qwh, qwl, qth, qtl, qlogp);
        k_main1<<<512, 256, 0, stream>>>(C, c_mask, q_mask, w1, qlogp, qwh, qwl, part, pimg);
        k_main2<<<512, 256, 0, stream>>>(C, part, qth, qtl, pimg, out);
    } else {
        float* qlog   = (float*)(wsb + 0);
        float* rowmax = (float*)(wsb + 196608);
        float* wq2c   = (float*)(wsb + 262144);
        float* bctx   = (float*)(wsb + 327680);
        k_qlogit<<<512, 256, 0, stream>>>(Q, w2, qlog);
        k_main_fb<<<512, 256, 0, stream>>>(C, Q, c_mask, q_mask, w1, w3, qlog, rowmax, out);
        k_q2c<<<16, 256, 0, stream>>>(rowmax, c_mask, wq2c);
        k_bctx<<<192, 256, 0, stream>>>(C, wq2c, bctx);
        k_final<<<16384, 192, 0, stream>>>(C, bctx, out);
    }
}

// Round 13
// 94.966 us; speedup vs baseline: 2.2901x; 1.0782x over previous
//
#include <hip/hip_runtime.h>
#include <math.h>
#include <stdint.h>

#define NEGV -1e9f
typedef float f32x4 __attribute__((ext_vector_type(4)));
typedef short bf16x8 __attribute__((ext_vector_type(8)));
typedef unsigned int u32x4 __attribute__((ext_vector_type(4)));

constexpr int B_ = 16, N_ = 1024, M_ = 128, D_ = 768;
constexpr int NCH = 12;  // 768/64 chunks

// ws layout (bytes):
constexpr size_t OFF_QLOGP  = 0;         // f32[16*128*12] = 98304
constexpr size_t OFF_BCTX   = 98304;     // (fallback only)
constexpr size_t OFF_PART   = 147456;    // 512 slots * 4096 B -> 2244608
constexpr size_t OFF_ROWMAX = 147456;    // fallback only (aliases PART)
constexpr size_t OFF_WQ2C   = 212992;    // fallback only (aliases PART)
constexpr size_t OFF_PIMG   = 2244608;   // 512 * 16384 -> 10633216
constexpr size_t OFF_QIMG   = 10633216;  // QwH,QwL,QtH,QtL
constexpr size_t SZ_QIMG    = 3145728;
constexpr size_t WS_NEED    = OFF_QIMG + 4 * SZ_QIMG;  // ~23.2 MB

__device__ __forceinline__ unsigned short bf_rne(float x) {
    unsigned u = __float_as_uint(x);
    return (unsigned short)((u + 0x7fffu + ((u >> 16) & 1u)) >> 16);
}
__device__ __forceinline__ void splitf(float x, unsigned short& h, unsigned short& l) {
    unsigned short hb = bf_rne(x);
    float hf = __uint_as_float((unsigned)hb << 16);
    h = hb;
    l = bf_rne(x - hf);
}
__device__ __forceinline__ void gl_lds16(const void* g, void* l) {
    __builtin_amdgcn_global_load_lds(
        (const __attribute__((address_space(1))) void*)g,
        (__attribute__((address_space(3))) void*)l, 16, 0, 0);
}

// ---------------- k_prep (R7/R8-verified) ----------------
__global__ __launch_bounds__(256) void k_prep(const float* __restrict__ Q,
                                              const float* __restrict__ w2,
                                              const float* __restrict__ w3,
                                              char* __restrict__ qwh, char* __restrict__ qwl,
                                              char* __restrict__ qth, char* __restrict__ qtl,
                                              float* __restrict__ qlogp) {
    int b = blockIdx.x / NCH, c = blockIdx.x % NCH;
    int t = threadIdx.x;
    __shared__ unsigned sT[128][66];
    __shared__ float sW2[64], sW3c[64];
    if (t < 64) sW2[t] = w2[c * 64 + t];
    else if (t < 128) sW3c[t - 64] = w3[c * 64 + (t - 64)];
    __syncthreads();
    int j = t >> 1, half = t & 1;
    const float* src = Q + ((size_t)(b * M_ + j)) * D_ + c * 64 + half * 32;
    unsigned short hs[32], ls[32];
    float qsum = 0.f;
#pragma unroll
    for (int u = 0; u < 8; ++u) {
        float4 v = *(const float4*)(src + u * 4);
        float f[4] = {v.x, v.y, v.z, v.w};
#pragma unroll
        for (int e = 0; e < 4; ++e) {
            int idx = u * 4 + e, d = half * 32 + idx;
            qsum += f[e] * sW2[d];
            unsigned short rh, rl; splitf(f[e], rh, rl);
            sT[j][d] = ((unsigned)rh << 16) | (unsigned)rl;
            unsigned short h, l; splitf(f[e] * sW3c[d], h, l);
            hs[idx] = h; ls[idx] = l;
        }
    }
    qsum += __shfl_xor(qsum, 1);
    if (half == 0) qlogp[(size_t)(b * M_ + j) * NCH + c] = qsum;
    size_t cb = ((size_t)(b * NCH + c)) * 16384;
    {
        int jh = j >> 6, jt = (j >> 4) & 3, c15j = j & 15;
#pragma unroll
        for (int u2 = 0; u2 < 4; ++u2) {
            int g = half * 4 + u2, ks = g >> 2, q4g = g & 3;
            int lane = q4g * 16 + c15j;
            bf16x8 hv, lv;
#pragma unroll
            for (int e = 0; e < 8; ++e) { hv[e] = (short)hs[u2 * 8 + e]; lv[e] = (short)ls[u2 * 8 + e]; }
            size_t off = cb + (size_t)((((jh * 2 + ks) * 4 + jt) * 64 + lane) * 16);
            *(bf16x8*)(qwh + off) = hv;
            *(bf16x8*)(qwl + off) = lv;
        }
    }
    __syncthreads();
#pragma unroll
    for (int u = 0; u < 4; ++u) {
        int id = t * 4 + u;
        int dd = id >> 4, gj = id & 15;
        int jh3 = dd >> 5, dt = (dd >> 4) & 1, c15q = dd & 15;
        int ks2 = gj >> 2, q4g = gj & 3;
        int lane = q4g * 16 + c15q;
        bf16x8 hv, lv;
#pragma unroll
        for (int e = 0; e < 8; ++e) {
            unsigned p = sT[gj * 8 + e][dd];
            hv[e] = (short)(p >> 16); lv[e] = (short)(p & 0xffffu);
        }
        size_t off = cb + (size_t)((((jh3 * 4 + ks2) * 2 + dt) * 64 + lane) * 16);
        *(bf16x8*)(qth + off) = hv;
        *(bf16x8*)(qtl + off) = lv;
    }
}

// ---------------- k_main1: phases 1+2 + Bctx partials + P dump (R9/R10-verified) ----------------
__global__ __launch_bounds__(256, 3) void k_main1(const float* __restrict__ C,
                                                  const int* __restrict__ c_mask,
                                                  const int* __restrict__ q_mask,
                                                  const float* __restrict__ w1,
                                                  const float* __restrict__ qlogp,
                                                  const char* __restrict__ qwh,
                                                  const char* __restrict__ qwl,
                                                  float* __restrict__ part,
                                                  char* __restrict__ pimg) {
    const int bid = (blockIdx.x & 7) * 64 + (blockIdx.x >> 3);  // XCD-chunked, bijective
    const int b  = bid >> 5;
    const int r0 = (bid & 31) * 32;
    const int t  = threadIdx.x;
    const int wv = t >> 6, lane = t & 63;
    const int rg = wv >> 1, jh = wv & 1;
    const int q4 = lane >> 4, c15 = t & 15;

    const float* Cb = C + ((size_t)(b * N_ + r0)) * D_;

    __shared__ __align__(16) char uni[49152];
    __shared__ float sQlog[M_];
    __shared__ int   sQmask[M_];
    __shared__ float sClog[32], sMraw[32], sMl[32], sWr[32];
    __shared__ float sRedR[64], sRedM[64], sRedS[64];

    char* sQH = uni;                 // phase1 B staging (16 KB)
    char* sQL = uni + 16384;
    char* sPH = uni + 32768;         // P image (8 KB) — written phase-2 tail
    char* sPL = uni + 40960;
    float* sW1 = (float*)(uni + 32768);  // aliases sPH; dead before P store

    for (int k = t; k < D_; k += 256) sW1[k] = w1[k];
    if (t < M_) {
        const float* qp = qlogp + (size_t)(b * M_ + t) * NCH;
        float4 x = *(const float4*)qp, y = *(const float4*)(qp + 4), z = *(const float4*)(qp + 8);
        sQlog[t] = ((x.x + x.y) + (x.z + x.w)) + ((y.x + y.y) + (y.z + y.w)) +
                   ((z.x + z.y) + (z.z + z.w));
        sQmask[t] = q_mask[b * M_ + t];
    }
    __syncthreads();

    f32x4 acc[4] = {};
    float clogp = 0.f;
    const int arow = rg * 16 + c15;
    const float* CbA = Cb + (size_t)arow * D_;
    const size_t qcb = (size_t)(b * NCH) * 16384;

    // ---- Phase 1: S = C @ (w3*Q)^T ----
    for (int kidx = 0; kidx < NCH; ++kidx) {
        __syncthreads();
        {
            size_t gb = qcb + (size_t)kidx * 16384;
#pragma unroll
            for (int it = 0; it < 4; ++it) {
                int qo = it * 4096 + wv * 1024;
                gl_lds16(qwh + gb + qo + lane * 16, sQH + qo);
                gl_lds16(qwl + gb + qo + lane * 16, sQL + qo);
            }
        }
        bf16x8 ah[2], al[2];
        const int kb = kidx * 64;
#pragma unroll
        for (int ks = 0; ks < 2; ++ks) {
            const int k0 = kb + (ks * 4 + q4) * 8;
            float4 ca  = *(const float4*)(CbA + k0);
            float4 cb2 = *(const float4*)(CbA + k0 + 4);
            float cc[8] = {ca.x, ca.y, ca.z, ca.w, cb2.x, cb2.y, cb2.z, cb2.w};
#pragma unroll
            for (int e = 0; e < 8; ++e) {
                clogp += cc[e] * sW1[k0 + e];
                unsigned short h, l; splitf(cc[e], h, l);
                ah[ks][e] = (short)h; al[ks][e] = (short)l;
            }
        }
        __syncthreads();
#pragma unroll
        for (int ks = 0; ks < 2; ++ks) {
#pragma unroll
            for (int jt = 0; jt < 4; ++jt) {
                int fo = (((jh * 2 + ks) * 4 + jt) * 64 + lane) * 16;
                bf16x8 bh = *(const bf16x8*)(sQH + fo);
                bf16x8 bl = *(const bf16x8*)(sQL + fo);
                acc[jt] = __builtin_amdgcn_mfma_f32_16x16x32_bf16(ah[ks], bh, acc[jt], 0, 0, 0);
                acc[jt] = __builtin_amdgcn_mfma_f32_16x16x32_bf16(ah[ks], bl, acc[jt], 0, 0, 0);
                acc[jt] = __builtin_amdgcn_mfma_f32_16x16x32_bf16(al[ks], bh, acc[jt], 0, 0, 0);
            }
        }
    }
    clogp += __shfl_xor(clogp, 16);
    clogp += __shfl_xor(clogp, 32);
    if (jh == 0 && q4 == 0) sClog[arow] = clogp;
    __syncthreads();

    // ---- Phase 2: logits + masked softmax ----
    float qlg[4]; int qmv[4];
#pragma unroll
    for (int jt = 0; jt < 4; ++jt) {
        int j = jh * 64 + jt * 16 + c15;
        qlg[jt] = sQlog[j]; qmv[jt] = sQmask[j];
    }
    int cmv[4]; float clgr[4];
#pragma unroll
    for (int rr = 0; rr < 4; ++rr) {
        int row = rg * 16 + q4 * 4 + rr;
        cmv[rr]  = c_mask[b * N_ + r0 + row];
        clgr[rr] = sClog[row];
    }
    float mv[4][4], rmx[4], mmx[4];
#pragma unroll
    for (int rr = 0; rr < 4; ++rr) { rmx[rr] = -INFINITY; mmx[rr] = -INFINITY; }
#pragma unroll
    for (int jt = 0; jt < 4; ++jt)
#pragma unroll
        for (int rr = 0; rr < 4; ++rr) {
            float val = acc[jt][rr] + clgr[rr] + qlg[jt];
            float m   = (cmv[rr] | qmv[jt]) ? NEGV : val;
            mv[jt][rr] = m;
            rmx[rr] = fmaxf(rmx[rr], val);
            mmx[rr] = fmaxf(mmx[rr], m);
        }
#pragma unroll
    for (int rr = 0; rr < 4; ++rr)
#pragma unroll
        for (int off = 8; off; off >>= 1) {
            rmx[rr] = fmaxf(rmx[rr], __shfl_xor(rmx[rr], off));
            mmx[rr] = fmaxf(mmx[rr], __shfl_xor(mmx[rr], off));
        }
    if (c15 == 0) {
#pragma unroll
        for (int rr = 0; rr < 4; ++rr) {
            int row = rg * 16 + q4 * 4 + rr;
            sRedR[row * 2 + jh] = rmx[rr];
            sRedM[row * 2 + jh] = mmx[rr];
        }
    }
    __syncthreads();
    float Mm[4], sum[4];
#pragma unroll
    for (int rr = 0; rr < 4; ++rr) {
        int row = rg * 16 + q4 * 4 + rr;
        float Mraw = fmaxf(sRedR[row * 2], sRedR[row * 2 + 1]);
        Mm[rr] = fmaxf(sRedM[row * 2], sRedM[row * 2 + 1]);
        if (jh == 0 && c15 == 0) sMraw[row] = Mraw;
        sum[rr] = 0.f;
    }
    float p[4][4];
#pragma unroll
    for (int jt = 0; jt < 4; ++jt)
#pragma unroll
        for (int rr = 0; rr < 4; ++rr) {
            float e = __expf(mv[jt][rr] - Mm[rr]);
            p[jt][rr] = e; sum[rr] += e;
        }
#pragma unroll
    for (int rr = 0; rr < 4; ++rr) {
#pragma unroll
        for (int off = 8; off; off >>= 1) sum[rr] += __shfl_xor(sum[rr], off);
        if (c15 == 0) sRedS[(rg * 16 + q4 * 4 + rr) * 2 + jh] = sum[rr];
    }
    __syncthreads();   // sW1 (alias of sPH) dead; safe to overwrite
#pragma unroll
    for (int rr = 0; rr < 4; ++rr) {
        int row = rg * 16 + q4 * 4 + rr;
        float inv = 1.f / (sRedS[row * 2] + sRedS[row * 2 + 1]);
#pragma unroll
        for (int jt = 0; jt < 4; ++jt) {
            float P = p[jt][rr] * inv;
            unsigned short h, l; splitf(P, h, l);
            int j = jh * 64 + jt * 16 + c15;
            int addr = row * 256 + (((j >> 3) ^ (row & 7)) * 16) + (j & 7) * 2;
            *(short*)(sPH + addr) = (short)h;
            *(short*)(sPL + addr) = (short)l;
        }
    }
    __syncthreads();

    // ---- Bctx partials (online softmax over this block's 32 rows) ----
    if (t < 32) sMl[t] = (c_mask[b * N_ + r0 + t] != 0) ? NEGV : sMraw[t];
    __syncthreads();
    float lm = -INFINITY;
#pragma unroll
    for (int r = 0; r < 32; ++r) lm = fmaxf(lm, sMl[r]);
    if (t < 32) sWr[t] = __expf(sMl[t] - lm);
    __syncthreads();
    float den = 0.f;
#pragma unroll
    for (int r = 0; r < 32; ++r) den += sWr[r];
    {
        float a0 = 0.f, a1 = 0.f, a2 = 0.f;
        for (int r = 0; r < 32; ++r) {
            float w = sWr[r];
            if (w != 0.f) {
                const float* cr = Cb + (size_t)r * D_;
                a0 += w * cr[t]; a1 += w * cr[t + 256]; a2 += w * cr[t + 512];
            }
        }
        float* slot = part + (size_t)bid * 1024;
        slot[2 + t] = a0; slot[2 + t + 256] = a1; slot[2 + t + 512] = a2;
        if (t == 0) { slot[0] = lm; slot[1] = den; }
    }
    // ---- dump P image ----
#pragma unroll
    for (int i = 0; i < 2; ++i) {
        *(u32x4*)(pimg + (size_t)bid * 16384 + t * 32 + i * 16) =
            *(const u32x4*)(sPH + t * 32 + i * 16);
        *(u32x4*)(pimg + (size_t)bid * 16384 + 8192 + t * 32 + i * 16) =
            *(const u32x4*)(sPL + t * 32 + i * 16);
    }
}

// ---------------- k_main2: inline combine + phase 3 + 4-quarter epilogue (R10-verified) ----------------
__global__ __launch_bounds__(256, 3) void k_main2(const float* __restrict__ C,
                                                  const float* __restrict__ part,
                                                  const char* __restrict__ qth,
                                                  const char* __restrict__ qtl,
                                                  const char* __restrict__ pimg,
                                                  float* __restrict__ out) {
    const int bid = (blockIdx.x & 7) * 64 + (blockIdx.x >> 3);  // same swizzle as main1
    const int b  = bid >> 5;
    const int r0 = (bid & 31) * 32;
    const int t  = threadIdx.x;
    const int wv = t >> 6, lane = t & 63;
    const int rg = wv >> 1, jh = wv & 1;
    const int q4 = lane >> 4, c15 = t & 15;

    const float* Cb = C + ((size_t)(b * N_ + r0)) * D_;

    __shared__ __align__(16) char uni[49152];
    __shared__ float sBctx[D_];
    __shared__ float sLm[32], sDen[32], sSc[32];
    char* sQtH = uni;             // Qt chunk staging (16 KB)
    char* sQtL = uni + 16384;
    char* sPH  = uni + 32768;     // P image (8 KB)
    char* sPL  = uni + 40960;

    {   // load P image (async) — flies under the combine compute below
        const char* ps = pimg + (size_t)bid * 16384;
#pragma unroll
        for (int it = 0; it < 2; ++it) {
            int off = it * 4096 + wv * 1024;
            gl_lds16(ps + off + lane * 16, sPH + off);
            gl_lds16(ps + 8192 + off + lane * 16, sPL + off);
        }
    }
    // ---- inline combine: exact Bctx from 32 partials of this batch ----
    if (t < 32) {
        const float* s = part + (size_t)(b * 32 + t) * 1024;
        sLm[t] = s[0]; sDen[t] = s[1];
    }
    __syncthreads();
    {
        float gm = -INFINITY;
#pragma unroll
        for (int r = 0; r < 32; ++r) gm = fmaxf(gm, sLm[r]);
        if (t < 32) sSc[t] = __expf(sLm[t] - gm);
        __syncthreads();
        float Ds = 0.f;
#pragma unroll
        for (int r = 0; r < 32; ++r) Ds += sDen[r] * sSc[r];
        float inv = 1.f / Ds;
#pragma unroll
        for (int u = 0; u < 3; ++u) {
            int col = t + u * 256;
            float a = 0.f;
            for (int rt = 0; rt < 32; ++rt)
                a += sSc[rt] * part[(size_t)(b * 32 + rt) * 1024 + 2 + col];
            sBctx[col] = a * inv;
        }
    }
    __syncthreads();

    bf16x8 pah[4], pal[4];
    const int prow = rg * 16 + c15;
#pragma unroll
    for (int ks2 = 0; ks2 < 4; ++ks2) {
        int gja = ks2 * 4 + q4;
        int pgp = (gja ^ (prow & 7)) * 16;
        pah[ks2] = *(const bf16x8*)(sPH + prow * 256 + pgp);
        pal[ks2] = *(const bf16x8*)(sPL + prow * 256 + pgp);
    }

    const size_t qcb = (size_t)(b * NCH) * 16384;
    for (int dc = 0; dc < NCH; ++dc) {
        __syncthreads();
        {
            size_t gb = qcb + (size_t)dc * 16384;
#pragma unroll
            for (int it = 0; it < 4; ++it) {
                int qo = it * 4096 + wv * 1024;
                gl_lds16(qth + gb + qo + lane * 16, sQtH + qo);
                gl_lds16(qtl + gb + qo + lane * 16, sQtL + qo);
            }
        }
        // prefetch epilogue C values + bctx while staging drains
        float cpre[2][4], gpre[2];
#pragma unroll
        for (int dt = 0; dt < 2; ++dt) {
            int dcol = dc * 64 + jh * 32 + dt * 16 + c15;
            gpre[dt] = sBctx[dcol];
#pragma unroll
            for (int rr = 0; rr < 4; ++rr) {
                int row = rg * 16 + q4 * 4 + rr;
                cpre[dt][rr] = Cb[(size_t)row * D_ + dcol];
            }
        }
        __syncthreads();
        f32x4 acc2[2] = {};
#pragma unroll
        for (int ks2 = 0; ks2 < 4; ++ks2) {
#pragma unroll
            for (int dt = 0; dt < 2; ++dt) {
                int fo = (((jh * 4 + ks2) * 2 + dt) * 64 + lane) * 16;
                bf16x8 bh = *(const bf16x8*)(sQtH + fo);
                bf16x8 bl = *(const bf16x8*)(sQtL + fo);
                acc2[dt] = __builtin_amdgcn_mfma_f32_16x16x32_bf16(pah[ks2], bh, acc2[dt], 0, 0, 0);
                acc2[dt] = __builtin_amdgcn_mfma_f32_16x16x32_bf16(pah[ks2], bl, acc2[dt], 0, 0, 0);
                acc2[dt] = __builtin_amdgcn_mfma_f32_16x16x32_bf16(pal[ks2], bh, acc2[dt], 0, 0, 0);
            }
        }
#pragma unroll
        for (int dt = 0; dt < 2; ++dt) {
            int dcol = dc * 64 + jh * 32 + dt * 16 + c15;
            float g = gpre[dt];
#pragma unroll
            for (int rr = 0; rr < 4; ++rr) {
                int row = rg * 16 + q4 * 4 + rr;
                float a = acc2[dt][rr];
                float c = cpre[dt][rr];
                size_t ob = (size_t)(b * N_ + r0 + row) * 3072;
                out[ob + dcol] = c;
                out[ob + 768 + dcol] = a;
                out[ob + 1536 + dcol] = c * a;
                out[ob + 2304 + dcol] = c * g;
            }
        }
    }
}

// ---------------- fallback chain (R2-proven) ----------------
__global__ __launch_bounds__(256) void k_qlogit(const float* __restrict__ Q,
                                                const float* __restrict__ w2,
                                                float* __restrict__ qlog) {
    int idx  = blockIdx.x * 4 + (threadIdx.x >> 6);
    int lane = threadIdx.x & 63;
    const float* q = Q + (size_t)idx * D_;
    float s = 0.f;
    for (int k = lane; k < D_; k += 64) s += q[k] * w2[k];
#pragma unroll
    for (int off = 32; off; off >>= 1) s += __shfl_xor(s, off);
    if (lane == 0) qlog[idx] = s;
}

__global__ __launch_bounds__(256, 2) void k_main_fb(const float* __restrict__ C,
                                                    const float* __restrict__ Q,
                                                    const int* __restrict__ c_mask,
                                                    const int* __restrict__ q_mask,
                                                    const float* __restrict__ w1,
                                                    const float* __restrict__ w3,
                                                    const float* __restrict__ qlog,
                                                    float* __restrict__ rowmax,
                                                    float* __restrict__ out) {
    const int bid = (blockIdx.x & 7) * 64 + (blockIdx.x >> 3);
    const int b  = bid >> 5;
    const int r0 = (bid & 31) * 32;
    const int t  = threadIdx.x;
    const int wv = t >> 6;
    const int rg = wv >> 1, jh = wv & 1;
    const int q4 = (t & 63) >> 4, c15 = t & 15;

    const float* Cb = C + ((size_t)(b * N_ + r0)) * D_;
    const float* Qb = Q + (size_t)b * M_ * D_;

    __shared__ __align__(16) char uni[49152];
    __shared__ float sW1[D_], sW3[D_];
    __shared__ float sQlog[M_];
    __shared__ int   sQmask[M_];
    __shared__ float sClog[32];
    __shared__ float sRedR[64], sRedM[64], sRedS[64];

    char* sCwH = uni;
    char* sCwL = uni + 4096;
    char* sQH  = uni + 8192;
    char* sQL  = uni + 24576;
    char* sPt  = uni;
    char* sQtP = uni + 16384;

    for (int k = t; k < D_; k += 256) { sW1[k] = w1[k]; sW3[k] = w3[k]; }
    if (t < M_) { sQlog[t] = qlog[b * M_ + t]; sQmask[t] = q_mask[b * M_ + t]; }

    f32x4 acc[4] = {};
    float clog = 0.f;
    const int cr = t >> 3, ckq = t & 7;
    const int qj = t >> 1, qk0 = (t & 1) * 32;

    for (int kb = 0; kb < D_; kb += 64) {
        __syncthreads();
        {
            const float* p = Cb + (size_t)cr * D_ + kb + ckq * 8;
            float4 a  = *(const float4*)p;
            float4 bb = *(const float4*)(p + 4);
            float cc[8] = {a.x, a.y, a.z, a.w, bb.x, bb.y, bb.z, bb.w};
            bf16x8 hv, lv;
            int kk = kb + ckq * 8;
#pragma unroll
            for (int e = 0; e < 8; ++e) {
                clog += cc[e] * sW1[kk + e];
                unsigned short h, l;
                splitf(cc[e] * sW3[kk + e], h, l);
                hv[e] = (short)h; lv[e] = (short)l;
            }
            int pg = (ckq ^ (cr & 7)) * 16;
            *(bf16x8*)(sCwH + cr * 128 + pg) = hv;
            *(bf16x8*)(sCwL + cr * 128 + pg) = lv;
        }
        {
            const float* p = Qb + (size_t)qj * D_ + kb + qk0;
#pragma unroll
            for (int u = 0; u < 4; ++u) {
                float4 a  = *(const float4*)(p + u * 8);
                float4 bb = *(const float4*)(p + u * 8 + 4);
                float qq[8] = {a.x, a.y, a.z, a.w, bb.x, bb.y, bb.z, bb.w};
                bf16x8 hv, lv;
#pragma unroll
                for (int e = 0; e < 8; ++e) {
                    unsigned short h, l;
                    splitf(qq[e], h, l);
                    hv[e] = (short)h; lv[e] = (short)l;
                }
                int g  = (t & 1) * 4 + u;
                int pg = (g ^ (qj & 7)) * 16;
                *(bf16x8*)(sQH + qj * 128 + pg) = hv;
                *(bf16x8*)(sQL + qj * 128 + pg) = lv;
            }
        }
        __syncthreads();
        const int arow = rg * 16 + c15;
#pragma unroll
        for (int ks = 0; ks < 2; ++ks) {
            int g  = ks * 4 + q4;
            int pg = (g ^ (c15 & 7)) * 16;
            bf16x8 ah = *(const bf16x8*)(sCwH + arow * 128 + pg);
            bf16x8 al = *(const bf16x8*)(sCwL + arow * 128 + pg);
#pragma unroll
            for (int jt = 0; jt < 4; ++jt) {
                int jr = jh * 64 + jt * 16 + c15;
                bf16x8 bh = *(const bf16x8*)(sQH + jr * 128 + pg);
                bf16x8 bl = *(const bf16x8*)(sQL + jr * 128 + pg);
                acc[jt] = __builtin_amdgcn_mfma_f32_16x16x32_bf16(ah, bh, acc[jt], 0, 0, 0);
                acc[jt] = __builtin_amdgcn_mfma_f32_16x16x32_bf16(ah, bl, acc[jt], 0, 0, 0);
                acc[jt] = __builtin_amdgcn_mfma_f32_16x16x32_bf16(al, bh, acc[jt], 0, 0, 0);
            }
        }
    }

    clog += __shfl_xor(clog, 1); clog += __shfl_xor(clog, 2); clog += __shfl_xor(clog, 4);
    if ((t & 7) == 0) sClog[cr] = clog;
    __syncthreads();

    float qlg[4]; int qmv[4];
#pragma unroll
    for (int jt = 0; jt < 4; ++jt) {
        int j = jh * 64 + jt * 16 + c15;
        qlg[jt] = sQlog[j]; qmv[jt] = sQmask[j];
    }
    int cmv[4]; float clgr[4];
#pragma unroll
    for (int rr = 0; rr < 4; ++rr) {
        int row = rg * 16 + q4 * 4 + rr;
        cmv[rr]  = c_mask[b * N_ + r0 + row];
        clgr[rr] = sClog[row];
    }
    float mv[4][4], rmx[4], mmx[4];
#pragma unroll
    for (int rr = 0; rr < 4; ++rr) { rmx[rr] = -INFINITY; mmx[rr] = -INFINITY; }
#pragma unroll
    for (int jt = 0; jt < 4; ++jt)
#pragma unroll
        for (int rr = 0; rr < 4; ++rr) {
            float val = acc[jt][rr] + clgr[rr] + qlg[jt];
            float m   = (cmv[rr] | qmv[jt]) ? NEGV : val;
            mv[jt][rr] = m;
            rmx[rr] = fmaxf(rmx[rr], val);
            mmx[rr] = fmaxf(mmx[rr], m);
        }
#pragma unroll
    for (int rr = 0; rr < 4; ++rr)
#pragma unroll
        for (int off = 8; off; off >>= 1) {
            rmx[rr] = fmaxf(rmx[rr], __shfl_xor(rmx[rr], off));
            mmx[rr] = fmaxf(mmx[rr], __shfl_xor(mmx[rr], off));
        }
    if (c15 == 0) {
#pragma unroll
        for (int rr = 0; rr < 4; ++rr) {
            int row = rg * 16 + q4 * 4 + rr;
            sRedR[row * 2 + jh] = rmx[rr];
            sRedM[row * 2 + jh] = mmx[rr];
        }
    }
    __syncthreads();
    float Mm[4], sum[4];
#pragma unroll
    for (int rr = 0; rr < 4; ++rr) {
        int row = rg * 16 + q4 * 4 + rr;
        float Mraw = fmaxf(sRedR[row * 2], sRedR[row * 2 + 1]);
        Mm[rr] = fmaxf(sRedM[row * 2], sRedM[row * 2 + 1]);
        if (jh == 0 && c15 == 0) rowmax[b * N_ + r0 + row] = Mraw;
        sum[rr] = 0.f;
    }
    float p[4][4];
#pragma unroll
    for (int jt = 0; jt < 4; ++jt)
#pragma unroll
        for (int rr = 0; rr < 4; ++rr) {
            float e = __expf(mv[jt][rr] - Mm[rr]);
            p[jt][rr] = e; sum[rr] += e;
        }
#pragma unroll
    for (int rr = 0; rr < 4; ++rr) {
#pragma unroll
        for (int off = 8; off; off >>= 1) sum[rr] += __shfl_xor(sum[rr], off);
        if (c15 == 0) sRedS[(rg * 16 + q4 * 4 + rr) * 2 + jh] = sum[rr];
    }
    __syncthreads();
#pragma unroll
    for (int rr = 0; rr < 4; ++rr) {
        int row = rg * 16 + q4 * 4 + rr;
        float inv = 1.f / (sRedS[row * 2] + sRedS[row * 2 + 1]);
#pragma unroll
        for (int jt = 0; jt < 4; ++jt) {
            float P = p[jt][rr] * inv;
            unsigned short h, l; splitf(P, h, l);
            unsigned pk = ((unsigned)h << 16) | (unsigned)l;
            int j  = jh * 64 + jt * 16 + c15;
            int gu = j >> 2;
            *(unsigned*)(sPt + row * 512 + ((gu ^ (row & 7)) * 16) + (j & 3) * 4) = pk;
        }
    }

    const int pj = t >> 1, pdh = (t & 1) * 32;
    for (int d0 = 0; d0 < D_; d0 += 64) {
        __syncthreads();
        {
            const float* p = Qb + (size_t)pj * D_ + d0 + pdh;
            int gu = pj >> 2, joff = (pj & 3) * 4;
#pragma unroll
            for (int u = 0; u < 8; ++u) {
                float4 a = *(const float4*)(p + u * 4);
                float qq[4] = {a.x, a.y, a.z, a.w};
#pragma unroll
                for (int e = 0; e < 4; ++e) {
                    unsigned short h, l; splitf(qq[e], h, l);
                    int d = pdh + u * 4 + e;
                    *(unsigned*)(sQtP + d * 512 + ((gu ^ (d & 7)) * 16) + joff) =
                        ((unsigned)h << 16) | (unsigned)l;
                }
            }
        }
        __syncthreads();
        f32x4 acc2[2] = {};
        const int prow = rg * 16 + c15;
#pragma unroll
        for (int ks2 = 0; ks2 < 4; ++ks2) {
            int gu0 = ks2 * 8 + q4 * 2;
            u32x4 pa = *(const u32x4*)(sPt + prow * 512 + ((gu0 ^ (c15 & 7)) * 16));
            u32x4 pb = *(const u32x4*)(sPt + prow * 512 + (((gu0 + 1) ^ (c15 & 7)) * 16));
            bf16x8 phi, plo;
#pragma unroll
            for (int e = 0; e < 4; ++e) {
                phi[e]     = (short)(pa[e] >> 16); plo[e]     = (short)(pa[e] & 0xffffu);
                phi[e + 4] = (short)(pb[e] >> 16); plo[e + 4] = (short)(pb[e] & 0xffffu);
            }
#pragma unroll
            for (int dt = 0; dt < 2; ++dt) {
                int dr = jh * 32 + dt * 16 + c15;
                u32x4 qa = *(const u32x4*)(sQtP + dr * 512 + ((gu0 ^ (dr & 7)) * 16));
                u32x4 qb = *(const u32x4*)(sQtP + dr * 512 + (((gu0 + 1) ^ (dr & 7)) * 16));
                bf16x8 bh, bl;
#pragma unroll
                for (int e = 0; e < 4; ++e) {
                    bh[e]     = (short)(qa[e] >> 16); bl[e]     = (short)(qa[e] & 0xffffu);
                    bh[e + 4] = (short)(qb[e] >> 16); bl[e + 4] = (short)(qb[e] & 0xffffu);
                }
                acc2[dt] = __builtin_amdgcn_mfma_f32_16x16x32_bf16(phi, bh, acc2[dt], 0, 0, 0);
                acc2[dt] = __builtin_amdgcn_mfma_f32_16x16x32_bf16(phi, bl, acc2[dt], 0, 0, 0);
                acc2[dt] = __builtin_amdgcn_mfma_f32_16x16x32_bf16(plo, bh, acc2[dt], 0, 0, 0);
            }
        }
#pragma unroll
        for (int dt = 0; dt < 2; ++dt)
#pragma unroll
            for (int rr = 0; rr < 4; ++rr) {
                int row  = rg * 16 + q4 * 4 + rr;
                int dcol = d0 + jh * 32 + dt * 16 + c15;
                float a = acc2[dt][rr];
                float c = Cb[(size_t)row * D_ + dcol];
                size_t ob = (size_t)(b * N_ + r0 + row) * 3072;
                out[ob + dcol] = c;
                out[ob + 768 + dcol] = a;
                out[ob + 1536 + dcol] = c * a;
            }
    }
}

__global__ __launch_bounds__(256) void k_q2c(const float* __restrict__ rowmax,
                                             const int* __restrict__ c_mask,
                                             float* __restrict__ wq2c) {
    int b = blockIdx.x, t = threadIdx.x;
    __shared__ float red[8];
    float l[4];
#pragma unroll
    for (int u = 0; u < 4; ++u) {
        int i = t + u * 256;
        l[u] = (c_mask[b * N_ + i] != 0) ? NEGV : rowmax[b * N_ + i];
    }
    float mx = fmaxf(fmaxf(l[0], l[1]), fmaxf(l[2], l[3]));
#pragma unroll
    for (int off = 32; off; off >>= 1) mx = fmaxf(mx, __shfl_xor(mx, off));
    if ((t & 63) == 0) red[t >> 6] = mx;
    __syncthreads();
    mx = fmaxf(fmaxf(red[0], red[1]), fmaxf(red[2], red[3]));
    float e[4], s = 0.f;
#pragma unroll
    for (int u = 0; u < 4; ++u) { e[u] = __expf(l[u] - mx); s += e[u]; }
#pragma unroll
    for (int off = 32; off; off >>= 1) s += __shfl_xor(s, off);
    if ((t & 63) == 0) red[4 + (t >> 6)] = s;
    __syncthreads();
    s = red[4] + red[5] + red[6] + red[7];
    float inv = 1.f / s;
#pragma unroll
    for (int u = 0; u < 4; ++u) wq2c[b * N_ + t + u * 256] = e[u] * inv;
}

__global__ __launch_bounds__(256) void k_bctx(const float* __restrict__ C,
                                              const float* __restrict__ wq2c,
                                              float* __restrict__ Bctx) {
    int b  = blockIdx.x / 12;
    int c0 = (blockIdx.x % 12) * 64;
    int t  = threadIdx.x;
    int col = t & 63, ig = t >> 6;
    __shared__ float part[4][64];
    const float* wb = wq2c + b * N_;
    const float* Cb = C + (size_t)b * N_ * D_;
    float s = 0.f;
    for (int i = ig * 256; i < ig * 256 + 256; ++i)
        s += wb[i] * Cb[(size_t)i * D_ + c0 + col];
    part[ig][col] = s;
    __syncthreads();
    if (t < 64) Bctx[b * D_ + c0 + t] = part[0][t] + part[1][t] + part[2][t] + part[3][t];
}

__global__ __launch_bounds__(192) void k_final(const float* __restrict__ C,
                                               const float* __restrict__ Bctx,
                                               float* __restrict__ out) {
    int row = blockIdx.x;
    int b = row >> 10;
    int t = threadIdx.x;
    float4 c = *(const float4*)(C + (size_t)row * D_ + t * 4);
    float4 g = *(const float4*)(Bctx + (size_t)b * D_ + t * 4);
    *(float4*)(out + (size_t)row * 3072 + 2304 + t * 4) =
        make_float4(c.x * g.x, c.y * g.y, c.z * g.z, c.w * g.w);
}

extern "C" void kernel_launch(void* const* d_in, const int* in_sizes, int n_in,
                              void* d_out, int out_size, void* d_ws, size_t ws_size,
                              hipStream_t stream) {
    const float* C      = (const float*)d_in[0];
    const float* Q      = (const float*)d_in[1];
    const int*   c_mask = (const int*)d_in[2];
    const int*   q_mask = (const int*)d_in[3];
    const float* w1     = (const float*)d_in[4];
    const float* w2     = (const float*)d_in[5];
    const float* w3     = (const float*)d_in[6];
    float* out = (float*)d_out;
    char*  wsb = (char*)d_ws;

    float* qlogp  = (float*)(wsb + OFF_QLOGP);
    float* part   = (float*)(wsb + OFF_PART);
    char*  pimg   = wsb + OFF_PIMG;

    if (ws_size >= WS_NEED) {
        char* qwh = wsb + OFF_QIMG;
        char* qwl = qwh + SZ_QIMG;
        char* qth = qwl + SZ_QIMG;
        char* qtl = qth + SZ_QIMG;
        k_prep<<<B_ * NCH, 256, 0, stream>>>(Q, w2, w3, qwh, qwl, qth, qtl, qlogp);
        k_main1<<<512, 256, 0, stream>>>(C, c_mask, q_mask, w1, qlogp, qwh, qwl, part, pimg);
        k_main2<<<512, 256, 0, stream>>>(C, part, qth, qtl, pimg, out);
    } else {
        float* qlog   = (float*)(wsb + OFF_QLOGP);
        float* rowmax = (float*)(wsb + OFF_ROWMAX);
        float* wq2c   = (float*)(wsb + OFF_WQ2C);
        float* bctx   = (float*)(wsb + OFF_BCTX);
        k_qlogit<<<512, 256, 0, stream>>>(Q, w2, qlog);
        k_main_fb<<<512, 256, 0, stream>>>(C, Q, c_mask, q_mask, w1, w3, qlog, rowmax, out);
        k_q2c<<<16, 256, 0, stream>>>(rowmax, c_mask, wq2c);
        k_bctx<<<192, 256, 0, stream>>>(C, wq2c, bctx);
        k_final<<<16384, 192, 0, stream>>>(C, bctx, out);
    }
}

// Round 14
// 94.042 us; speedup vs baseline: 2.3127x; 1.0098x over previous
//
#include <hip/hip_runtime.h>
#include <math.h>
#include <stdint.h>

#define NEGV -1e9f
typedef float f32x4 __attribute__((ext_vector_type(4)));
typedef short bf16x8 __attribute__((ext_vector_type(8)));
typedef unsigned int u32x4 __attribute__((ext_vector_type(4)));

constexpr int B_ = 16, N_ = 1024, M_ = 128, D_ = 768;
constexpr int NCH = 12;  // 768/64 chunks

// ws layout (bytes):
constexpr size_t OFF_QLOGP  = 0;         // f32[16*128*12] = 98304
constexpr size_t OFF_BCTX   = 98304;     // (fallback only)
constexpr size_t OFF_PART   = 147456;    // 512 slots * 4096 B -> 2244608
constexpr size_t OFF_ROWMAX = 147456;    // fallback only (aliases PART)
constexpr size_t OFF_WQ2C   = 212992;    // fallback only (aliases PART)
constexpr size_t OFF_PIMG   = 2244608;   // 512 * 16384 -> 10633216
constexpr size_t OFF_QIMG   = 10633216;  // QwH,QwL,QtH,QtL
constexpr size_t SZ_QIMG    = 3145728;
constexpr size_t WS_NEED    = OFF_QIMG + 4 * SZ_QIMG;  // ~23.2 MB

__device__ __forceinline__ unsigned short bf_rne(float x) {
    unsigned u = __float_as_uint(x);
    return (unsigned short)((u + 0x7fffu + ((u >> 16) & 1u)) >> 16);
}
__device__ __forceinline__ void splitf(float x, unsigned short& h, unsigned short& l) {
    unsigned short hb = bf_rne(x);
    float hf = __uint_as_float((unsigned)hb << 16);
    h = hb;
    l = bf_rne(x - hf);
}
__device__ __forceinline__ void gl_lds16(const void* g, void* l) {
    __builtin_amdgcn_global_load_lds(
        (const __attribute__((address_space(1))) void*)g,
        (__attribute__((address_space(3))) void*)l, 16, 0, 0);
}

// ---------------- k_prep (R7/R8-verified) ----------------
__global__ __launch_bounds__(256) void k_prep(const float* __restrict__ Q,
                                              const float* __restrict__ w2,
                                              const float* __restrict__ w3,
                                              char* __restrict__ qwh, char* __restrict__ qwl,
                                              char* __restrict__ qth, char* __restrict__ qtl,
                                              float* __restrict__ qlogp) {
    int b = blockIdx.x / NCH, c = blockIdx.x % NCH;
    int t = threadIdx.x;
    __shared__ unsigned sT[128][66];
    __shared__ float sW2[64], sW3c[64];
    if (t < 64) sW2[t] = w2[c * 64 + t];
    else if (t < 128) sW3c[t - 64] = w3[c * 64 + (t - 64)];
    __syncthreads();
    int j = t >> 1, half = t & 1;
    const float* src = Q + ((size_t)(b * M_ + j)) * D_ + c * 64 + half * 32;
    unsigned short hs[32], ls[32];
    float qsum = 0.f;
#pragma unroll
    for (int u = 0; u < 8; ++u) {
        float4 v = *(const float4*)(src + u * 4);
        float f[4] = {v.x, v.y, v.z, v.w};
#pragma unroll
        for (int e = 0; e < 4; ++e) {
            int idx = u * 4 + e, d = half * 32 + idx;
            qsum += f[e] * sW2[d];
            unsigned short rh, rl; splitf(f[e], rh, rl);
            sT[j][d] = ((unsigned)rh << 16) | (unsigned)rl;
            unsigned short h, l; splitf(f[e] * sW3c[d], h, l);
            hs[idx] = h; ls[idx] = l;
        }
    }
    qsum += __shfl_xor(qsum, 1);
    if (half == 0) qlogp[(size_t)(b * M_ + j) * NCH + c] = qsum;
    size_t cb = ((size_t)(b * NCH + c)) * 16384;
    {
        int jh = j >> 6, jt = (j >> 4) & 3, c15j = j & 15;
#pragma unroll
        for (int u2 = 0; u2 < 4; ++u2) {
            int g = half * 4 + u2, ks = g >> 2, q4g = g & 3;
            int lane = q4g * 16 + c15j;
            bf16x8 hv, lv;
#pragma unroll
            for (int e = 0; e < 8; ++e) { hv[e] = (short)hs[u2 * 8 + e]; lv[e] = (short)ls[u2 * 8 + e]; }
            size_t off = cb + (size_t)((((jh * 2 + ks) * 4 + jt) * 64 + lane) * 16);
            *(bf16x8*)(qwh + off) = hv;
            *(bf16x8*)(qwl + off) = lv;
        }
    }
    __syncthreads();
#pragma unroll
    for (int u = 0; u < 4; ++u) {
        int id = t * 4 + u;
        int dd = id >> 4, gj = id & 15;
        int jh3 = dd >> 5, dt = (dd >> 4) & 1, c15q = dd & 15;
        int ks2 = gj >> 2, q4g = gj & 3;
        int lane = q4g * 16 + c15q;
        bf16x8 hv, lv;
#pragma unroll
        for (int e = 0; e < 8; ++e) {
            unsigned p = sT[gj * 8 + e][dd];
            hv[e] = (short)(p >> 16); lv[e] = (short)(p & 0xffffu);
        }
        size_t off = cb + (size_t)((((jh3 * 4 + ks2) * 2 + dt) * 64 + lane) * 16);
        *(bf16x8*)(qth + off) = hv;
        *(bf16x8*)(qtl + off) = lv;
    }
}

// ---------------- k_main1: phases 1+2 + Bctx partials + P dump (R9/R10-verified) ----------------
__global__ __launch_bounds__(256, 3) void k_main1(const float* __restrict__ C,
                                                  const int* __restrict__ c_mask,
                                                  const int* __restrict__ q_mask,
                                                  const float* __restrict__ w1,
                                                  const float* __restrict__ qlogp,
                                                  const char* __restrict__ qwh,
                                                  const char* __restrict__ qwl,
                                                  float* __restrict__ part,
                                                  char* __restrict__ pimg) {
    const int bid = (blockIdx.x & 7) * 64 + (blockIdx.x >> 3);  // XCD-chunked, bijective
    const int b  = bid >> 5;
    const int r0 = (bid & 31) * 32;
    const int t  = threadIdx.x;
    const int wv = t >> 6, lane = t & 63;
    const int rg = wv >> 1, jh = wv & 1;
    const int q4 = lane >> 4, c15 = t & 15;

    const float* Cb = C + ((size_t)(b * N_ + r0)) * D_;

    __shared__ __align__(16) char uni[49152];
    __shared__ float sQlog[M_];
    __shared__ int   sQmask[M_];
    __shared__ float sClog[32], sMraw[32], sMl[32], sWr[32];
    __shared__ float sRedR[64], sRedM[64], sRedS[64];

    char* sQH = uni;                 // phase1 B staging (16 KB)
    char* sQL = uni + 16384;
    char* sPH = uni + 32768;         // P image (8 KB) — written phase-2 tail
    char* sPL = uni + 40960;
    float* sW1 = (float*)(uni + 32768);  // aliases sPH; dead before P store

    for (int k = t; k < D_; k += 256) sW1[k] = w1[k];
    if (t < M_) {
        const float* qp = qlogp + (size_t)(b * M_ + t) * NCH;
        float4 x = *(const float4*)qp, y = *(const float4*)(qp + 4), z = *(const float4*)(qp + 8);
        sQlog[t] = ((x.x + x.y) + (x.z + x.w)) + ((y.x + y.y) + (y.z + y.w)) +
                   ((z.x + z.y) + (z.z + z.w));
        sQmask[t] = q_mask[b * M_ + t];
    }
    __syncthreads();

    f32x4 acc[4] = {};
    float clogp = 0.f;
    const int arow = rg * 16 + c15;
    const float* CbA = Cb + (size_t)arow * D_;
    const size_t qcb = (size_t)(b * NCH) * 16384;

    // ---- Phase 1: S = C @ (w3*Q)^T ----
    for (int kidx = 0; kidx < NCH; ++kidx) {
        __syncthreads();
        {
            size_t gb = qcb + (size_t)kidx * 16384;
#pragma unroll
            for (int it = 0; it < 4; ++it) {
                int qo = it * 4096 + wv * 1024;
                gl_lds16(qwh + gb + qo + lane * 16, sQH + qo);
                gl_lds16(qwl + gb + qo + lane * 16, sQL + qo);
            }
        }
        bf16x8 ah[2], al[2];
        const int kb = kidx * 64;
#pragma unroll
        for (int ks = 0; ks < 2; ++ks) {
            const int k0 = kb + (ks * 4 + q4) * 8;
            float4 ca  = *(const float4*)(CbA + k0);
            float4 cb2 = *(const float4*)(CbA + k0 + 4);
            float cc[8] = {ca.x, ca.y, ca.z, ca.w, cb2.x, cb2.y, cb2.z, cb2.w};
#pragma unroll
            for (int e = 0; e < 8; ++e) {
                clogp += cc[e] * sW1[k0 + e];
                unsigned short h, l; splitf(cc[e], h, l);
                ah[ks][e] = (short)h; al[ks][e] = (short)l;
            }
        }
        __syncthreads();
#pragma unroll
        for (int ks = 0; ks < 2; ++ks) {
#pragma unroll
            for (int jt = 0; jt < 4; ++jt) {
                int fo = (((jh * 2 + ks) * 4 + jt) * 64 + lane) * 16;
                bf16x8 bh = *(const bf16x8*)(sQH + fo);
                bf16x8 bl = *(const bf16x8*)(sQL + fo);
                acc[jt] = __builtin_amdgcn_mfma_f32_16x16x32_bf16(ah[ks], bh, acc[jt], 0, 0, 0);
                acc[jt] = __builtin_amdgcn_mfma_f32_16x16x32_bf16(ah[ks], bl, acc[jt], 0, 0, 0);
                acc[jt] = __builtin_amdgcn_mfma_f32_16x16x32_bf16(al[ks], bh, acc[jt], 0, 0, 0);
            }
        }
    }
    clogp += __shfl_xor(clogp, 16);
    clogp += __shfl_xor(clogp, 32);
    if (jh == 0 && q4 == 0) sClog[arow] = clogp;
    __syncthreads();

    // ---- Phase 2: logits + masked softmax ----
    float qlg[4]; int qmv[4];
#pragma unroll
    for (int jt = 0; jt < 4; ++jt) {
        int j = jh * 64 + jt * 16 + c15;
        qlg[jt] = sQlog[j]; qmv[jt] = sQmask[j];
    }
    int cmv[4]; float clgr[4];
#pragma unroll
    for (int rr = 0; rr < 4; ++rr) {
        int row = rg * 16 + q4 * 4 + rr;
        cmv[rr]  = c_mask[b * N_ + r0 + row];
        clgr[rr] = sClog[row];
    }
    float mv[4][4], rmx[4], mmx[4];
#pragma unroll
    for (int rr = 0; rr < 4; ++rr) { rmx[rr] = -INFINITY; mmx[rr] = -INFINITY; }
#pragma unroll
    for (int jt = 0; jt < 4; ++jt)
#pragma unroll
        for (int rr = 0; rr < 4; ++rr) {
            float val = acc[jt][rr] + clgr[rr] + qlg[jt];
            float m   = (cmv[rr] | qmv[jt]) ? NEGV : val;
            mv[jt][rr] = m;
            rmx[rr] = fmaxf(rmx[rr], val);
            mmx[rr] = fmaxf(mmx[rr], m);
        }
#pragma unroll
    for (int rr = 0; rr < 4; ++rr)
#pragma unroll
        for (int off = 8; off; off >>= 1) {
            rmx[rr] = fmaxf(rmx[rr], __shfl_xor(rmx[rr], off));
            mmx[rr] = fmaxf(mmx[rr], __shfl_xor(mmx[rr], off));
        }
    if (c15 == 0) {
#pragma unroll
        for (int rr = 0; rr < 4; ++rr) {
            int row = rg * 16 + q4 * 4 + rr;
            sRedR[row * 2 + jh] = rmx[rr];
            sRedM[row * 2 + jh] = mmx[rr];
        }
    }
    __syncthreads();
    float Mm[4], sum[4];
#pragma unroll
    for (int rr = 0; rr < 4; ++rr) {
        int row = rg * 16 + q4 * 4 + rr;
        float Mraw = fmaxf(sRedR[row * 2], sRedR[row * 2 + 1]);
        Mm[rr] = fmaxf(sRedM[row * 2], sRedM[row * 2 + 1]);
        if (jh == 0 && c15 == 0) sMraw[row] = Mraw;
        sum[rr] = 0.f;
    }
    float p[4][4];
#pragma unroll
    for (int jt = 0; jt < 4; ++jt)
#pragma unroll
        for (int rr = 0; rr < 4; ++rr) {
            float e = __expf(mv[jt][rr] - Mm[rr]);
            p[jt][rr] = e; sum[rr] += e;
        }
#pragma unroll
    for (int rr = 0; rr < 4; ++rr) {
#pragma unroll
        for (int off = 8; off; off >>= 1) sum[rr] += __shfl_xor(sum[rr], off);
        if (c15 == 0) sRedS[(rg * 16 + q4 * 4 + rr) * 2 + jh] = sum[rr];
    }
    __syncthreads();   // sW1 (alias of sPH) dead; safe to overwrite
#pragma unroll
    for (int rr = 0; rr < 4; ++rr) {
        int row = rg * 16 + q4 * 4 + rr;
        float inv = 1.f / (sRedS[row * 2] + sRedS[row * 2 + 1]);
#pragma unroll
        for (int jt = 0; jt < 4; ++jt) {
            float P = p[jt][rr] * inv;
            unsigned short h, l; splitf(P, h, l);
            int j = jh * 64 + jt * 16 + c15;
            int addr = row * 256 + (((j >> 3) ^ (row & 7)) * 16) + (j & 7) * 2;
            *(short*)(sPH + addr) = (short)h;
            *(short*)(sPL + addr) = (short)l;
        }
    }
    __syncthreads();

    // ---- Bctx partials (online softmax over this block's 32 rows) ----
    if (t < 32) sMl[t] = (c_mask[b * N_ + r0 + t] != 0) ? NEGV : sMraw[t];
    __syncthreads();
    float lm = -INFINITY;
#pragma unroll
    for (int r = 0; r < 32; ++r) lm = fmaxf(lm, sMl[r]);
    if (t < 32) sWr[t] = __expf(sMl[t] - lm);
    __syncthreads();
    float den = 0.f;
#pragma unroll
    for (int r = 0; r < 32; ++r) den += sWr[r];
    {
        float a0 = 0.f, a1 = 0.f, a2 = 0.f;
        for (int r = 0; r < 32; ++r) {
            float w = sWr[r];
            if (w != 0.f) {
                const float* cr = Cb + (size_t)r * D_;
                a0 += w * cr[t]; a1 += w * cr[t + 256]; a2 += w * cr[t + 512];
            }
        }
        float* slot = part + (size_t)bid * 1024;
        slot[2 + t] = a0; slot[2 + t + 256] = a1; slot[2 + t + 512] = a2;
        if (t == 0) { slot[0] = lm; slot[1] = den; }
    }
    // ---- dump P image ----
#pragma unroll
    for (int i = 0; i < 2; ++i) {
        *(u32x4*)(pimg + (size_t)bid * 16384 + t * 32 + i * 16) =
            *(const u32x4*)(sPH + t * 32 + i * 16);
        *(u32x4*)(pimg + (size_t)bid * 16384 + 8192 + t * 32 + i * 16) =
            *(const u32x4*)(sPL + t * 32 + i * 16);
    }
}

// ---------------- k_main2: inline combine + phase 3 (Q single-bf16) + 4-quarter epilogue ----------------
// R14: Qt-lo dropped (|ΔA| ~ |Q|*2^-9 ~ 0.01, threshold 0.3875). LDS 52->36 KB, 4 blocks/CU.
__global__ __launch_bounds__(256, 4) void k_main2(const float* __restrict__ C,
                                                  const float* __restrict__ part,
                                                  const char* __restrict__ qth,
                                                  const char* __restrict__ qtl,
                                                  const char* __restrict__ pimg,
                                                  float* __restrict__ out) {
    const int bid = (blockIdx.x & 7) * 64 + (blockIdx.x >> 3);  // same swizzle as main1
    const int b  = bid >> 5;
    const int r0 = (bid & 31) * 32;
    const int t  = threadIdx.x;
    const int wv = t >> 6, lane = t & 63;
    const int rg = wv >> 1, jh = wv & 1;
    const int q4 = lane >> 4, c15 = t & 15;

    const float* Cb = C + ((size_t)(b * N_ + r0)) * D_;

    __shared__ __align__(16) char uni[32768];
    __shared__ float sBctx[D_];
    __shared__ float sLm[32], sDen[32], sSc[32];
    char* sQtH = uni;             // Qt chunk staging, hi only (16 KB)
    char* sPH  = uni + 16384;     // P image (8 KB)
    char* sPL  = uni + 24576;

    {   // load P image (async) — flies under the combine compute below
        const char* ps = pimg + (size_t)bid * 16384;
#pragma unroll
        for (int it = 0; it < 2; ++it) {
            int off = it * 4096 + wv * 1024;
            gl_lds16(ps + off + lane * 16, sPH + off);
            gl_lds16(ps + 8192 + off + lane * 16, sPL + off);
        }
    }
    // ---- inline combine: exact Bctx from 32 partials of this batch ----
    if (t < 32) {
        const float* s = part + (size_t)(b * 32 + t) * 1024;
        sLm[t] = s[0]; sDen[t] = s[1];
    }
    __syncthreads();
    {
        float gm = -INFINITY;
#pragma unroll
        for (int r = 0; r < 32; ++r) gm = fmaxf(gm, sLm[r]);
        if (t < 32) sSc[t] = __expf(sLm[t] - gm);
        __syncthreads();
        float Ds = 0.f;
#pragma unroll
        for (int r = 0; r < 32; ++r) Ds += sDen[r] * sSc[r];
        float inv = 1.f / Ds;
#pragma unroll
        for (int u = 0; u < 3; ++u) {
            int col = t + u * 256;
            float a = 0.f;
            for (int rt = 0; rt < 32; ++rt)
                a += sSc[rt] * part[(size_t)(b * 32 + rt) * 1024 + 2 + col];
            sBctx[col] = a * inv;
        }
    }
    __syncthreads();

    bf16x8 pah[4], pal[4];
    const int prow = rg * 16 + c15;
#pragma unroll
    for (int ks2 = 0; ks2 < 4; ++ks2) {
        int gja = ks2 * 4 + q4;
        int pgp = (gja ^ (prow & 7)) * 16;
        pah[ks2] = *(const bf16x8*)(sPH + prow * 256 + pgp);
        pal[ks2] = *(const bf16x8*)(sPL + prow * 256 + pgp);
    }

    const size_t qcb = (size_t)(b * NCH) * 16384;
    for (int dc = 0; dc < NCH; ++dc) {
        __syncthreads();
        {
            size_t gb = qcb + (size_t)dc * 16384;
#pragma unroll
            for (int it = 0; it < 4; ++it) {
                int qo = it * 4096 + wv * 1024;
                gl_lds16(qth + gb + qo + lane * 16, sQtH + qo);
            }
        }
        // prefetch epilogue C values + bctx while staging drains
        float cpre[2][4], gpre[2];
#pragma unroll
        for (int dt = 0; dt < 2; ++dt) {
            int dcol = dc * 64 + jh * 32 + dt * 16 + c15;
            gpre[dt] = sBctx[dcol];
#pragma unroll
            for (int rr = 0; rr < 4; ++rr) {
                int row = rg * 16 + q4 * 4 + rr;
                cpre[dt][rr] = Cb[(size_t)row * D_ + dcol];
            }
        }
        __syncthreads();
        f32x4 acc2[2] = {};
#pragma unroll
        for (int ks2 = 0; ks2 < 4; ++ks2) {
#pragma unroll
            for (int dt = 0; dt < 2; ++dt) {
                int fo = (((jh * 4 + ks2) * 2 + dt) * 64 + lane) * 16;
                bf16x8 bh = *(const bf16x8*)(sQtH + fo);
                acc2[dt] = __builtin_amdgcn_mfma_f32_16x16x32_bf16(pah[ks2], bh, acc2[dt], 0, 0, 0);
                acc2[dt] = __builtin_amdgcn_mfma_f32_16x16x32_bf16(pal[ks2], bh, acc2[dt], 0, 0, 0);
            }
        }
#pragma unroll
        for (int dt = 0; dt < 2; ++dt) {
            int dcol = dc * 64 + jh * 32 + dt * 16 + c15;
            float g = gpre[dt];
#pragma unroll
            for (int rr = 0; rr < 4; ++rr) {
                int row = rg * 16 + q4 * 4 + rr;
                float a = acc2[dt][rr];
                float c = cpre[dt][rr];
                size_t ob = (size_t)(b * N_ + r0 + row) * 3072;
                out[ob + dcol] = c;
                out[ob + 768 + dcol] = a;
                out[ob + 1536 + dcol] = c * a;
                out[ob + 2304 + dcol] = c * g;
            }
        }
    }
}

// ---------------- fallback chain (R2-proven) ----------------
__global__ __launch_bounds__(256) void k_qlogit(const float* __restrict__ Q,
                                                const float* __restrict__ w2,
                                                float* __restrict__ qlog) {
    int idx  = blockIdx.x * 4 + (threadIdx.x >> 6);
    int lane = threadIdx.x & 63;
    const float* q = Q + (size_t)idx * D_;
    float s = 0.f;
    for (int k = lane; k < D_; k += 64) s += q[k] * w2[k];
#pragma unroll
    for (int off = 32; off; off >>= 1) s += __shfl_xor(s, off);
    if (lane == 0) qlog[idx] = s;
}

__global__ __launch_bounds__(256, 2) void k_main_fb(const float* __restrict__ C,
                                                    const float* __restrict__ Q,
                                                    const int* __restrict__ c_mask,
                                                    const int* __restrict__ q_mask,
                                                    const float* __restrict__ w1,
                                                    const float* __restrict__ w3,
                                                    const float* __restrict__ qlog,
                                                    float* __restrict__ rowmax,
                                                    float* __restrict__ out) {
    const int bid = (blockIdx.x & 7) * 64 + (blockIdx.x >> 3);
    const int b  = bid >> 5;
    const int r0 = (bid & 31) * 32;
    const int t  = threadIdx.x;
    const int wv = t >> 6;
    const int rg = wv >> 1, jh = wv & 1;
    const int q4 = (t & 63) >> 4, c15 = t & 15;

    const float* Cb = C + ((size_t)(b * N_ + r0)) * D_;
    const float* Qb = Q + (size_t)b * M_ * D_;

    __shared__ __align__(16) char uni[49152];
    __shared__ float sW1[D_], sW3[D_];
    __shared__ float sQlog[M_];
    __shared__ int   sQmask[M_];
    __shared__ float sClog[32];
    __shared__ float sRedR[64], sRedM[64], sRedS[64];

    char* sCwH = uni;
    char* sCwL = uni + 4096;
    char* sQH  = uni + 8192;
    char* sQL  = uni + 24576;
    char* sPt  = uni;
    char* sQtP = uni + 16384;

    for (int k = t; k < D_; k += 256) { sW1[k] = w1[k]; sW3[k] = w3[k]; }
    if (t < M_) { sQlog[t] = qlog[b * M_ + t]; sQmask[t] = q_mask[b * M_ + t]; }

    f32x4 acc[4] = {};
    float clog = 0.f;
    const int cr = t >> 3, ckq = t & 7;
    const int qj = t >> 1, qk0 = (t & 1) * 32;

    for (int kb = 0; kb < D_; kb += 64) {
        __syncthreads();
        {
            const float* p = Cb + (size_t)cr * D_ + kb + ckq * 8;
            float4 a  = *(const float4*)p;
            float4 bb = *(const float4*)(p + 4);
            float cc[8] = {a.x, a.y, a.z, a.w, bb.x, bb.y, bb.z, bb.w};
            bf16x8 hv, lv;
            int kk = kb + ckq * 8;
#pragma unroll
            for (int e = 0; e < 8; ++e) {
                clog += cc[e] * sW1[kk + e];
                unsigned short h, l;
                splitf(cc[e] * sW3[kk + e], h, l);
                hv[e] = (short)h; lv[e] = (short)l;
            }
            int pg = (ckq ^ (cr & 7)) * 16;
            *(bf16x8*)(sCwH + cr * 128 + pg) = hv;
            *(bf16x8*)(sCwL + cr * 128 + pg) = lv;
        }
        {
            const float* p = Qb + (size_t)qj * D_ + kb + qk0;
#pragma unroll
            for (int u = 0; u < 4; ++u) {
                float4 a  = *(const float4*)(p + u * 8);
                float4 bb = *(const float4*)(p + u * 8 + 4);
                float qq[8] = {a.x, a.y, a.z, a.w, bb.x, bb.y, bb.z, bb.w};
                bf16x8 hv, lv;
#pragma unroll
                for (int e = 0; e < 8; ++e) {
                    unsigned short h, l;
                    splitf(qq[e], h, l);
                    hv[e] = (short)h; lv[e] = (short)l;
                }
                int g  = (t & 1) * 4 + u;
                int pg = (g ^ (qj & 7)) * 16;
                *(bf16x8*)(sQH + qj * 128 + pg) = hv;
                *(bf16x8*)(sQL + qj * 128 + pg) = lv;
            }
        }
        __syncthreads();
        const int arow = rg * 16 + c15;
#pragma unroll
        for (int ks = 0; ks < 2; ++ks) {
            int g  = ks * 4 + q4;
            int pg = (g ^ (c15 & 7)) * 16;
            bf16x8 ah = *(const bf16x8*)(sCwH + arow * 128 + pg);
            bf16x8 al = *(const bf16x8*)(sCwL + arow * 128 + pg);
#pragma unroll
            for (int jt = 0; jt < 4; ++jt) {
                int jr = jh * 64 + jt * 16 + c15;
                bf16x8 bh = *(const bf16x8*)(sQH + jr * 128 + pg);
                bf16x8 bl = *(const bf16x8*)(sQL + jr * 128 + pg);
                acc[jt] = __builtin_amdgcn_mfma_f32_16x16x32_bf16(ah, bh, acc[jt], 0, 0, 0);
                acc[jt] = __builtin_amdgcn_mfma_f32_16x16x32_bf16(ah, bl, acc[jt], 0, 0, 0);
                acc[jt] = __builtin_amdgcn_mfma_f32_16x16x32_bf16(al, bh, acc[jt], 0, 0, 0);
            }
        }
    }

    clog += __shfl_xor(clog, 1); clog += __shfl_xor(clog, 2); clog += __shfl_xor(clog, 4);
    if ((t & 7) == 0) sClog[cr] = clog;
    __syncthreads();

    float qlg[4]; int qmv[4];
#pragma unroll
    for (int jt = 0; jt < 4; ++jt) {
        int j = jh * 64 + jt * 16 + c15;
        qlg[jt] = sQlog[j]; qmv[jt] = sQmask[j];
    }
    int cmv[4]; float clgr[4];
#pragma unroll
    for (int rr = 0; rr < 4; ++rr) {
        int row = rg * 16 + q4 * 4 + rr;
        cmv[rr]  = c_mask[b * N_ + r0 + row];
        clgr[rr] = sClog[row];
    }
    float mv[4][4], rmx[4], mmx[4];
#pragma unroll
    for (int rr = 0; rr < 4; ++rr) { rmx[rr] = -INFINITY; mmx[rr] = -INFINITY; }
#pragma unroll
    for (int jt = 0; jt < 4; ++jt)
#pragma unroll
        for (int rr = 0; rr < 4; ++rr) {
            float val = acc[jt][rr] + clgr[rr] + qlg[jt];
            float m   = (cmv[rr] | qmv[jt]) ? NEGV : val;
            mv[jt][rr] = m;
            rmx[rr] = fmaxf(rmx[rr], val);
            mmx[rr] = fmaxf(mmx[rr], m);
        }
#pragma unroll
    for (int rr = 0; rr < 4; ++rr)
#pragma unroll
        for (int off = 8; off; off >>= 1) {
            rmx[rr] = fmaxf(rmx[rr], __shfl_xor(rmx[rr], off));
            mmx[rr] = fmaxf(mmx[rr], __shfl_xor(mmx[rr], off));
        }
    if (c15 == 0) {
#pragma unroll
        for (int rr = 0; rr < 4; ++rr) {
            int row = rg * 16 + q4 * 4 + rr;
            sRedR[row * 2 + jh] = rmx[rr];
            sRedM[row * 2 + jh] = mmx[rr];
        }
    }
    __syncthreads();
    float Mm[4], sum[4];
#pragma unroll
    for (int rr = 0; rr < 4; ++rr) {
        int row = rg * 16 + q4 * 4 + rr;
        float Mraw = fmaxf(sRedR[row * 2], sRedR[row * 2 + 1]);
        Mm[rr] = fmaxf(sRedM[row * 2], sRedM[row * 2 + 1]);
        if (jh == 0 && c15 == 0) rowmax[b * N_ + r0 + row] = Mraw;
        sum[rr] = 0.f;
    }
    float p[4][4];
#pragma unroll
    for (int jt = 0; jt < 4; ++jt)
#pragma unroll
        for (int rr = 0; rr < 4; ++rr) {
            float e = __expf(mv[jt][rr] - Mm[rr]);
            p[jt][rr] = e; sum[rr] += e;
        }
#pragma unroll
    for (int rr = 0; rr < 4; ++rr) {
#pragma unroll
        for (int off = 8; off; off >>= 1) sum[rr] += __shfl_xor(sum[rr], off);
        if (c15 == 0) sRedS[(rg * 16 + q4 * 4 + rr) * 2 + jh] = sum[rr];
    }
    __syncthreads();
#pragma unroll
    for (int rr = 0; rr < 4; ++rr) {
        int row = rg * 16 + q4 * 4 + rr;
        float inv = 1.f / (sRedS[row * 2] + sRedS[row * 2 + 1]);
#pragma unroll
        for (int jt = 0; jt < 4; ++jt) {
            float P = p[jt][rr] * inv;
            unsigned short h, l; splitf(P, h, l);
            unsigned pk = ((unsigned)h << 16) | (unsigned)l;
            int j  = jh * 64 + jt * 16 + c15;
            int gu = j >> 2;
            *(unsigned*)(sPt + row * 512 + ((gu ^ (row & 7)) * 16) + (j & 3) * 4) = pk;
        }
    }

    const int pj = t >> 1, pdh = (t & 1) * 32;
    for (int d0 = 0; d0 < D_; d0 += 64) {
        __syncthreads();
        {
            const float* p = Qb + (size_t)pj * D_ + d0 + pdh;
            int gu = pj >> 2, joff = (pj & 3) * 4;
#pragma unroll
            for (int u = 0; u < 8; ++u) {
                float4 a = *(const float4*)(p + u * 4);
                float qq[4] = {a.x, a.y, a.z, a.w};
#pragma unroll
                for (int e = 0; e < 4; ++e) {
                    unsigned short h, l; splitf(qq[e], h, l);
                    int d = pdh + u * 4 + e;
                    *(unsigned*)(sQtP + d * 512 + ((gu ^ (d & 7)) * 16) + joff) =
                        ((unsigned)h << 16) | (unsigned)l;
                }
            }
        }
        __syncthreads();
        f32x4 acc2[2] = {};
        const int prow = rg * 16 + c15;
#pragma unroll
        for (int ks2 = 0; ks2 < 4; ++ks2) {
            int gu0 = ks2 * 8 + q4 * 2;
            u32x4 pa = *(const u32x4*)(sPt + prow * 512 + ((gu0 ^ (c15 & 7)) * 16));
            u32x4 pb = *(const u32x4*)(sPt + prow * 512 + (((gu0 + 1) ^ (c15 & 7)) * 16));
            bf16x8 phi, plo;
#pragma unroll
            for (int e = 0; e < 4; ++e) {
                phi[e]     = (short)(pa[e] >> 16); plo[e]     = (short)(pa[e] & 0xffffu);
                phi[e + 4] = (short)(pb[e] >> 16); plo[e + 4] = (short)(pb[e] & 0xffffu);
            }
#pragma unroll
            for (int dt = 0; dt < 2; ++dt) {
                int dr = jh * 32 + dt * 16 + c15;
                u32x4 qa = *(const u32x4*)(sQtP + dr * 512 + ((gu0 ^ (dr & 7)) * 16));
                u32x4 qb = *(const u32x4*)(sQtP + dr * 512 + (((gu0 + 1) ^ (dr & 7)) * 16));
                bf16x8 bh, bl;
#pragma unroll
                for (int e = 0; e < 4; ++e) {
                    bh[e]     = (short)(qa[e] >> 16); bl[e]     = (short)(qa[e] & 0xffffu);
                    bh[e + 4] = (short)(qb[e] >> 16); bl[e + 4] = (short)(qb[e] & 0xffffu);
                }
                acc2[dt] = __builtin_amdgcn_mfma_f32_16x16x32_bf16(phi, bh, acc2[dt], 0, 0, 0);
                acc2[dt] = __builtin_amdgcn_mfma_f32_16x16x32_bf16(phi, bl, acc2[dt], 0, 0, 0);
                acc2[dt] = __builtin_amdgcn_mfma_f32_16x16x32_bf16(plo, bh, acc2[dt], 0, 0, 0);
            }
        }
#pragma unroll
        for (int dt = 0; dt < 2; ++dt)
#pragma unroll
            for (int rr = 0; rr < 4; ++rr) {
                int row  = rg * 16 + q4 * 4 + rr;
                int dcol = d0 + jh * 32 + dt * 16 + c15;
                float a = acc2[dt][rr];
                float c = Cb[(size_t)row * D_ + dcol];
                size_t ob = (size_t)(b * N_ + r0 + row) * 3072;
                out[ob + dcol] = c;
                out[ob + 768 + dcol] = a;
                out[ob + 1536 + dcol] = c * a;
            }
    }
}

__global__ __launch_bounds__(256) void k_q2c(const float* __restrict__ rowmax,
                                             const int* __restrict__ c_mask,
                                             float* __restrict__ wq2c) {
    int b = blockIdx.x, t = threadIdx.x;
    __shared__ float red[8];
    float l[4];
#pragma unroll
    for (int u = 0; u < 4; ++u) {
        int i = t + u * 256;
        l[u] = (c_mask[b * N_ + i] != 0) ? NEGV : rowmax[b * N_ + i];
    }
    float mx = fmaxf(fmaxf(l[0], l[1]), fmaxf(l[2], l[3]));
#pragma unroll
    for (int off = 32; off; off >>= 1) mx = fmaxf(mx, __shfl_xor(mx, off));
    if ((t & 63) == 0) red[t >> 6] = mx;
    __syncthreads();
    mx = fmaxf(fmaxf(red[0], red[1]), fmaxf(red[2], red[3]));
    float e[4], s = 0.f;
#pragma unroll
    for (int u = 0; u < 4; ++u) { e[u] = __expf(l[u] - mx); s += e[u]; }
#pragma unroll
    for (int off = 32; off; off >>= 1) s += __shfl_xor(s, off);
    if ((t & 63) == 0) red[4 + (t >> 6)] = s;
    __syncthreads();
    s = red[4] + red[5] + red[6] + red[7];
    float inv = 1.f / s;
#pragma unroll
    for (int u = 0; u < 4; ++u) wq2c[b * N_ + t + u * 256] = e[u] * inv;
}

__global__ __launch_bounds__(256) void k_bctx(const float* __restrict__ C,
                                              const float* __restrict__ wq2c,
                                              float* __restrict__ Bctx) {
    int b  = blockIdx.x / 12;
    int c0 = (blockIdx.x % 12) * 64;
    int t  = threadIdx.x;
    int col = t & 63, ig = t >> 6;
    __shared__ float part[4][64];
    const float* wb = wq2c + b * N_;
    const float* Cb = C + (size_t)b * N_ * D_;
    float s = 0.f;
    for (int i = ig * 256; i < ig * 256 + 256; ++i)
        s += wb[i] * Cb[(size_t)i * D_ + c0 + col];
    part[ig][col] = s;
    __syncthreads();
    if (t < 64) Bctx[b * D_ + c0 + t] = part[0][t] + part[1][t] + part[2][t] + part[3][t];
}

__global__ __launch_bounds__(192) void k_final(const float* __restrict__ C,
                                               const float* __restrict__ Bctx,
                                               float* __restrict__ out) {
    int row = blockIdx.x;
    int b = row >> 10;
    int t = threadIdx.x;
    float4 c = *(const float4*)(C + (size_t)row * D_ + t * 4);
    float4 g = *(const float4*)(Bctx + (size_t)b * D_ + t * 4);
    *(float4*)(out + (size_t)row * 3072 + 2304 + t * 4) =
        make_float4(c.x * g.x, c.y * g.y, c.z * g.z, c.w * g.w);
}

extern "C" void kernel_launch(void* const* d_in, const int* in_sizes, int n_in,
                              void* d_out, int out_size, void* d_ws, size_t ws_size,
                              hipStream_t stream) {
    const float* C      = (const float*)d_in[0];
    const float* Q      = (const float*)d_in[1];
    const int*   c_mask = (const int*)d_in[2];
    const int*   q_mask = (const int*)d_in[3];
    const float* w1     = (const float*)d_in[4];
    const float* w2     = (const float*)d_in[5];
    const float* w3     = (const float*)d_in[6];
    float* out = (float*)d_out;
    char*  wsb = (char*)d_ws;

    float* qlogp  = (float*)(wsb + OFF_QLOGP);
    float* part   = (float*)(wsb + OFF_PART);
    char*  pimg   = wsb + OFF_PIMG;

    if (ws_size >= WS_NEED) {
        char* qwh = wsb + OFF_QIMG;
        char* qwl = qwh + SZ_QIMG;
        char* qth = qwl + SZ_QIMG;
        char* qtl = qth + SZ_QIMG;
        k_prep<<<B_ * NCH, 256, 0, stream>>>(Q, w2, w3, qwh, qwl, qth, qtl, qlogp);
        k_main1<<<512, 256, 0, stream>>>(C, c_mask, q_mask, w1, qlogp, qwh, qwl, part, pimg);
        k_main2<<<512, 256, 0, stream>>>(C, part, qth, qtl, pimg, out);
    } else {
        float* qlog   = (float*)(wsb + OFF_QLOGP);
        float* rowmax = (float*)(wsb + OFF_ROWMAX);
        float* wq2c   = (float*)(wsb + OFF_WQ2C);
        float* bctx   = (float*)(wsb + OFF_BCTX);
        k_qlogit<<<512, 256, 0, stream>>>(Q, w2, qlog);
        k_main_fb<<<512, 256, 0, stream>>>(C, Q, c_mask, q_mask, w1, w3, qlog, rowmax, out);
        k_q2c<<<16, 256, 0, stream>>>(rowmax, c_mask, wq2c);
        k_bctx<<<192, 256, 0, stream>>>(C, wq2c, bctx);
        k_final<<<16384, 192, 0, stream>>>(C, bctx, out);
    }
}